// Round 1
// baseline (3715.648 us; speedup 1.0000x reference)
//
#include <hip/hip_runtime.h>
#include <math.h>

#define EDIM 768
#define DDIM 192
#define E3 2304

// ---------------- mask statistics ----------------
__global__ void mask_stats1(const int* __restrict__ am, float* __restrict__ wsum,
                            float* __restrict__ svalid) {
  int n = blockIdx.x * blockDim.x + threadIdx.x;
  if (n < 1024) {
    int s = 0;
    const int* p = am + (size_t)n * 64;
    for (int w = 0; w < 64; ++w) s += p[w];
    wsum[n] = (float)s;
    svalid[n] = s > 0 ? 1.f : 0.f;
  }
}

__global__ void mask_stats2(const float* __restrict__ wsum, const float* __restrict__ svalid,
                            float* __restrict__ cnt2, float* __restrict__ secv,
                            float* __restrict__ cnt3) {
  int tid = threadIdx.x;  // 64 threads
  if (tid < 64) {
    float c = 0.f, t = 0.f;
    for (int u = 0; u < 16; ++u) { c += svalid[tid * 16 + u]; t += wsum[tid * 16 + u]; }
    cnt2[tid] = c;
    secv[tid] = t > 0.f ? 1.f : 0.f;
  }
  __syncthreads();
  if (tid < 8) {
    float c = 0.f;
    for (int s = 0; s < 8; ++s) c += secv[tid * 8 + s];
    cnt3[tid] = c;
  }
}

// ---------------- fp32 GEMM: out[m,n] = sum_k X[m,k]*W[n,k] + bias[n]*sfac(m) ----------------
#define BM 64
#define BN 64
#define BK 16
__global__ __launch_bounds__(256) void gemm_nt(
    const float* __restrict__ X, const float* __restrict__ W,
    const float* __restrict__ bias, const float* __restrict__ cnt,
    float* __restrict__ out, int M, int N, int K) {
  __shared__ float As[BK][BM + 4];
  __shared__ float Bs[BK][BN + 4];
  const int tid = threadIdx.x;
  const int m0 = blockIdx.y * BM;
  const int n0 = blockIdx.x * BN;
  const int tx = tid & 15, ty = tid >> 4;
  const int lr = tid >> 2;
  const int lc = (tid & 3) * 4;
  float acc[4][4];
#pragma unroll
  for (int i = 0; i < 4; ++i)
#pragma unroll
    for (int j = 0; j < 4; ++j) acc[i][j] = 0.f;
  for (int k0 = 0; k0 < K; k0 += BK) {
    float4 xa = make_float4(0.f, 0.f, 0.f, 0.f);
    if (m0 + lr < M) xa = *(const float4*)(X + (size_t)(m0 + lr) * K + k0 + lc);
    float4 wb = *(const float4*)(W + (size_t)(n0 + lr) * K + k0 + lc);
    As[lc + 0][lr] = xa.x; As[lc + 1][lr] = xa.y; As[lc + 2][lr] = xa.z; As[lc + 3][lr] = xa.w;
    Bs[lc + 0][lr] = wb.x; Bs[lc + 1][lr] = wb.y; Bs[lc + 2][lr] = wb.z; Bs[lc + 3][lr] = wb.w;
    __syncthreads();
#pragma unroll
    for (int kk = 0; kk < BK; ++kk) {
      float4 av = *(const float4*)&As[kk][ty * 4];
      float4 bv = *(const float4*)&Bs[kk][tx * 4];
      float a4[4] = {av.x, av.y, av.z, av.w};
      float b4[4] = {bv.x, bv.y, bv.z, bv.w};
#pragma unroll
      for (int i = 0; i < 4; ++i)
#pragma unroll
        for (int j = 0; j < 4; ++j) acc[i][j] += a4[i] * b4[j];
    }
    __syncthreads();
  }
#pragma unroll
  for (int i = 0; i < 4; ++i) {
    int m = m0 + ty * 4 + i;
    if (m < M) {
      float sf = 1.f;
      if (cnt) { float c = cnt[m]; sf = c / (c + 1e-10f); }
      float4 o;
      o.x = acc[i][0] + bias[n0 + tx * 4 + 0] * sf;
      o.y = acc[i][1] + bias[n0 + tx * 4 + 1] * sf;
      o.z = acc[i][2] + bias[n0 + tx * 4 + 2] * sf;
      o.w = acc[i][3] + bias[n0 + tx * 4 + 3] * sf;
      *(float4*)(out + (size_t)m * N + n0 + tx * 4) = o;
    }
  }
}

// ---------------- word-level attention (L=64), pooled output per (seq,head) ----------------
__global__ __launch_bounds__(256) void word_attn(
    const float* __restrict__ qkv, const int* __restrict__ am,
    const float* __restrict__ wsum, float* __restrict__ obar, int s0) {
  const int nl = blockIdx.x;
  const int h = blockIdx.y;
  const int n = s0 + nl;
  const int tid = threadIdx.x;
  __shared__ float qs[64][65];
  __shared__ float ks[64][65];
  __shared__ float red[64][65];
  __shared__ float abar[64];
  __shared__ float msk[64];
  const float* qb = qkv + (size_t)nl * 64 * E3 + h * DDIM;
  const float* kb = qb + EDIM;
  const float* vb = qb + 2 * EDIM;
  if (tid < 64) msk[tid] = (am[(size_t)n * 64 + tid] > 0) ? 1.f : 0.f;
  const int l = tid >> 2;
  const int mg = (tid & 3) * 16;
  float sc[16];
#pragma unroll
  for (int j = 0; j < 16; ++j) sc[j] = 0.f;
  for (int dd0 = 0; dd0 < DDIM; dd0 += 64) {
    for (int it = 0; it < 4; ++it) {
      int i4 = tid + it * 256;
      int r = i4 >> 4;
      int c = (i4 & 15) * 4;
      float4 qv4 = *(const float4*)(qb + (size_t)r * E3 + dd0 + c);
      float4 kv4 = *(const float4*)(kb + (size_t)r * E3 + dd0 + c);
      qs[r][c] = qv4.x; qs[r][c + 1] = qv4.y; qs[r][c + 2] = qv4.z; qs[r][c + 3] = qv4.w;
      ks[r][c] = kv4.x; ks[r][c + 1] = kv4.y; ks[r][c + 2] = kv4.z; ks[r][c + 3] = kv4.w;
    }
    __syncthreads();
    for (int c = 0; c < 64; ++c) {
      float qv = qs[l][c];
#pragma unroll
      for (int j = 0; j < 16; ++j) sc[j] += qv * ks[mg + j][c];
    }
    __syncthreads();
  }
  const float scale = 0.07216878364870323f;  // 1/sqrt(192)
  float mx = -1e30f;
#pragma unroll
  for (int j = 0; j < 16; ++j) {
    float s = (msk[mg + j] > 0.f) ? sc[j] * scale : -1e9f;
    sc[j] = s;
    mx = fmaxf(mx, s);
  }
  mx = fmaxf(mx, __shfl_xor(mx, 1));
  mx = fmaxf(mx, __shfl_xor(mx, 2));
  float sum = 0.f;
#pragma unroll
  for (int j = 0; j < 16; ++j) { float p = expf(sc[j] - mx); sc[j] = p; sum += p; }
  sum += __shfl_xor(sum, 1);
  sum += __shfl_xor(sum, 2);
  float den = wsum[n] + 1e-10f;
  float wl = (msk[l] > 0.f) ? (1.f / den) : 0.f;
  float inv = wl / sum;
#pragma unroll
  for (int j = 0; j < 16; ++j) red[l][mg + j] = sc[j] * inv;
  __syncthreads();
  if (tid < 64) {
    float s = 0.f;
    for (int l2 = 0; l2 < 64; ++l2) s += red[l2][tid];
    abar[tid] = s;
  }
  __syncthreads();
  if (tid < 192) {
    float acc = 0.f;
    for (int m = 0; m < 64; ++m) acc += abar[m] * vb[(size_t)m * E3 + tid];
    obar[(size_t)n * EDIM + h * DDIM + tid] = acc;
  }
}

// ---------------- small attention (L=16 or 8), pooled output ----------------
__global__ __launch_bounds__(256) void small_attn(
    const float* __restrict__ qkv, const float* __restrict__ maskv,
    const float* __restrict__ cnt, float* __restrict__ obar, int L) {
  const int n = blockIdx.x;
  const int h = blockIdx.y;
  const int tid = threadIdx.x;
  __shared__ float red[16][17];
  __shared__ float abar[16];
  const float* qb = qkv + (size_t)n * L * E3 + h * DDIM;
  const float* kb = qb + EDIM;
  const float* vb = qb + 2 * EDIM;
  const float scale = 0.07216878364870323f;
  if (tid < L * L) {
    int l = tid / L, m = tid % L;
    float s = 0.f;
    for (int dd = 0; dd < DDIM; ++dd) s += qb[(size_t)l * E3 + dd] * kb[(size_t)m * E3 + dd];
    s = (maskv[n * L + m] > 0.f) ? s * scale : -1e9f;
    float mx = s;
    for (int off = L >> 1; off > 0; off >>= 1) mx = fmaxf(mx, __shfl_xor(mx, off));
    float p = expf(s - mx);
    float sum = p;
    for (int off = L >> 1; off > 0; off >>= 1) sum += __shfl_xor(sum, off);
    float den = cnt[n] + 1e-10f;
    float wl = (maskv[n * L + l] > 0.f) ? (1.f / den) : 0.f;
    red[l][m] = p / sum * wl;
  }
  __syncthreads();
  if (tid < L) {
    float s = 0.f;
    for (int l2 = 0; l2 < L; ++l2) s += red[l2][tid];
    abar[tid] = s;
  }
  __syncthreads();
  if (tid < 192) {
    float acc = 0.f;
    for (int m = 0; m < L; ++m) acc += abar[m] * vb[(size_t)m * E3 + tid];
    obar[(size_t)n * EDIM + h * DDIM + tid] = acc;
  }
}

// ---------------- fusion head: [8,768] doc -> [8,3] ----------------
__global__ __launch_bounds__(256) void head_kernel(
    const float* __restrict__ doc, const float* __restrict__ hand,
    const float* __restrict__ bp_w, const float* __restrict__ bp_b,
    const float* __restrict__ hp_w, const float* __restrict__ hp_b,
    const float* __restrict__ gate_w, const float* __restrict__ gate_b,
    const float* __restrict__ fg, const float* __restrict__ fbv,
    const float* __restrict__ fc1_w, const float* __restrict__ fc1_b,
    const float* __restrict__ g1, const float* __restrict__ b1,
    const float* __restrict__ fc2_w, const float* __restrict__ fc2_b,
    float* __restrict__ out) {
  int b = blockIdx.x, tid = threadIdx.x;
  __shared__ float bp[256], hp[256], fz[256], hz[128];
  const float* dr = doc + (size_t)b * 768;
  float acc = bp_b[tid];
  for (int k = 0; k < 768; ++k) acc += dr[k] * bp_w[(size_t)tid * 768 + k];
  bp[tid] = acc;
  const float* hr = hand + b * 20;
  float acc2 = hp_b[tid];
  for (int k = 0; k < 20; ++k) acc2 += hr[k] * hp_w[tid * 20 + k];
  hp[tid] = acc2;
  __syncthreads();
  float g = gate_b[tid];
  for (int k = 0; k < 256; ++k) g += bp[k] * gate_w[tid * 512 + k];
  for (int k = 0; k < 256; ++k) g += hp[k] * gate_w[tid * 512 + 256 + k];
  g = 1.f / (1.f + expf(-g));
  float fu = g * bp[tid] + (1.f - g) * hp[tid];
  fz[tid] = fu;
  __syncthreads();
  float mu = 0.f;
  for (int k = 0; k < 256; ++k) mu += fz[k];
  mu /= 256.f;
  float va = 0.f;
  for (int k = 0; k < 256; ++k) { float d = fz[k] - mu; va += d * d; }
  va /= 256.f;
  float fl = (fu - mu) / sqrtf(va + 1e-5f) * fg[tid] + fbv[tid];
  __syncthreads();
  fz[tid] = fl;
  __syncthreads();
  if (tid < 128) {
    float a = fc1_b[tid];
    for (int k = 0; k < 256; ++k) a += fz[k] * fc1_w[tid * 256 + k];
    hz[tid] = fmaxf(a, 0.f);
  }
  __syncthreads();
  float mu2 = 0.f;
  for (int k = 0; k < 128; ++k) mu2 += hz[k];
  mu2 /= 128.f;
  float va2 = 0.f;
  for (int k = 0; k < 128; ++k) { float d = hz[k] - mu2; va2 += d * d; }
  va2 /= 128.f;
  __syncthreads();
  if (tid < 128) hz[tid] = (hz[tid] - mu2) / sqrtf(va2 + 1e-5f) * g1[tid] + b1[tid];
  __syncthreads();
  if (tid < 3) {
    float o = fc2_b[tid];
    for (int k = 0; k < 128; ++k) o += hz[k] * fc2_w[tid * 128 + k];
    out[b * 3 + tid] = o;
  }
}

extern "C" void kernel_launch(void* const* d_in, const int* in_sizes, int n_in,
                              void* d_out, int out_size, void* d_ws, size_t ws_size,
                              hipStream_t stream) {
  const float* we      = (const float*)d_in[0];
  const int*   am      = (const int*)d_in[1];
  const float* hand    = (const float*)d_in[2];
  const float* w_w_in  = (const float*)d_in[3];
  const float* w_b_in  = (const float*)d_in[4];
  const float* w_w_out = (const float*)d_in[5];
  const float* w_b_out = (const float*)d_in[6];
  const float* s_w_in  = (const float*)d_in[7];
  const float* s_b_in  = (const float*)d_in[8];
  const float* s_w_out = (const float*)d_in[9];
  const float* s_b_out = (const float*)d_in[10];
  const float* c_w_in  = (const float*)d_in[11];
  const float* c_b_in  = (const float*)d_in[12];
  const float* c_w_out = (const float*)d_in[13];
  const float* c_b_out = (const float*)d_in[14];
  const float* bp_w = (const float*)d_in[15];
  const float* bp_b = (const float*)d_in[16];
  const float* hp_w = (const float*)d_in[17];
  const float* hp_b = (const float*)d_in[18];
  // d_in[19..22] = fa_* (cross-attention) — output unused by the reference, skipped.
  const float* gate_w = (const float*)d_in[23];
  const float* gate_b = (const float*)d_in[24];
  const float* fus_g  = (const float*)d_in[25];
  const float* fus_b  = (const float*)d_in[26];
  const float* fc1_w  = (const float*)d_in[27];
  const float* fc1_b  = (const float*)d_in[28];
  const float* ln1_g  = (const float*)d_in[29];
  const float* ln1_b  = (const float*)d_in[30];
  const float* fc2_w  = (const float*)d_in[31];
  const float* fc2_b  = (const float*)d_in[32];
  float* out = (float*)d_out;

  // carve small buffers from the top of the workspace
  char* end = (char*)d_ws + ws_size;
  auto carve = [&](size_t nflt) {
    size_t b = (nflt * 4 + 255) & ~(size_t)255;
    end -= b;
    return (float*)end;
  };
  float* obar1  = carve(1024 * 768);
  float* sent   = carve(1024 * 768);
  float* qkv2   = carve(1024 * 2304);
  float* obar2  = carve(64 * 768);
  float* sec    = carve(64 * 768);
  float* qkv3   = carve(64 * 2304);
  float* obar3  = carve(8 * 768);
  float* doc    = carve(8 * 768);
  float* wsum   = carve(1024);
  float* svalid = carve(1024);
  float* cnt2   = carve(64);
  float* secv   = carve(64);
  float* cnt3   = carve(8);
  float* qkv1 = (float*)d_ws;
  size_t avail = (size_t)(end - (char*)d_ws);
  int cs = 1024;  // chunk of word-level sequences per pass
  while (cs > 16 && (size_t)cs * 64 * 2304 * 4 > avail) cs >>= 1;

  mask_stats1<<<4, 256, 0, stream>>>(am, wsum, svalid);
  mask_stats2<<<1, 64, 0, stream>>>(wsum, svalid, cnt2, secv, cnt3);

  for (int s0 = 0; s0 < 1024; s0 += cs) {
    int c = (1024 - s0 < cs) ? (1024 - s0) : cs;
    int M = c * 64;
    gemm_nt<<<dim3(2304 / 64, M / 64), 256, 0, stream>>>(
        we + (size_t)s0 * 64 * 768, w_w_in, w_b_in, nullptr, qkv1, M, 2304, 768);
    word_attn<<<dim3(c, 4), 256, 0, stream>>>(qkv1, am, wsum, obar1, s0);
  }
  // sent = obar1 @ w_out.T + b_out * sfac
  gemm_nt<<<dim3(12, 16), 256, 0, stream>>>(obar1, w_w_out, w_b_out, wsum, sent, 1024, 768, 768);
  // sentence level
  gemm_nt<<<dim3(36, 16), 256, 0, stream>>>(sent, s_w_in, s_b_in, nullptr, qkv2, 1024, 2304, 768);
  small_attn<<<dim3(64, 4), 256, 0, stream>>>(qkv2, svalid, cnt2, obar2, 16);
  gemm_nt<<<dim3(12, 1), 256, 0, stream>>>(obar2, s_w_out, s_b_out, cnt2, sec, 64, 768, 768);
  // section level
  gemm_nt<<<dim3(36, 1), 256, 0, stream>>>(sec, c_w_in, c_b_in, nullptr, qkv3, 64, 2304, 768);
  small_attn<<<dim3(8, 4), 256, 0, stream>>>(qkv3, secv, cnt3, obar3, 8);
  gemm_nt<<<dim3(12, 1), 256, 0, stream>>>(obar3, c_w_out, c_b_out, cnt3, doc, 8, 768, 768);
  // fusion head
  head_kernel<<<8, 256, 0, stream>>>(doc, hand, bp_w, bp_b, hp_w, hp_b, gate_w, gate_b,
                                     fus_g, fus_b, fc1_w, fc1_b, ln1_g, ln1_b, fc2_w, fc2_b, out);
}

// Round 2
// 1128.767 us; speedup vs baseline: 3.2918x; 3.2918x over previous
//
#include <hip/hip_runtime.h>
#include <math.h>

#define EDIM 768
#define DDIM 192
#define E3 2304

typedef __attribute__((ext_vector_type(8))) short short8;
typedef __attribute__((ext_vector_type(8))) unsigned short ushort8;
typedef __attribute__((ext_vector_type(4))) float f32x4;

__device__ inline void gload_lds16(const void* g, void* l) {
  __builtin_amdgcn_global_load_lds((const __attribute__((address_space(1))) void*)g,
                                   (__attribute__((address_space(3))) void*)l, 16, 0, 0);
}

__device__ inline unsigned short f2b_rne(float f) {
  unsigned int u = __builtin_bit_cast(unsigned int, f);
  u = (u + 0x7fffu + ((u >> 16) & 1u)) >> 16;
  return (unsigned short)u;
}

// ---------------- fp32 -> bf16 conversion (vectorized, grid-stride) ----------------
__global__ __launch_bounds__(256) void f2bf(const float* __restrict__ in,
                                            unsigned short* __restrict__ out, size_t n) {
  size_t i = ((size_t)blockIdx.x * blockDim.x + threadIdx.x) * 8;
  size_t stride = (size_t)gridDim.x * blockDim.x * 8;
  for (; i < n; i += stride) {
    float4 a = *(const float4*)(in + i);
    float4 b = *(const float4*)(in + i + 4);
    ushort8 o;
    o[0] = f2b_rne(a.x); o[1] = f2b_rne(a.y); o[2] = f2b_rne(a.z); o[3] = f2b_rne(a.w);
    o[4] = f2b_rne(b.x); o[5] = f2b_rne(b.y); o[6] = f2b_rne(b.z); o[7] = f2b_rne(b.w);
    *(ushort8*)(out + i) = o;
  }
}

// ---------------- bf16 MFMA GEMM (NT): C[m,n] = sum_k A[m,k]*B[n,k] + bias[n] ------
// 128x128 tile, 4 waves (2x2), mfma_f32_16x16x32_bf16, BK=32, global_load_lds staging.
// Requires M%128==0, N%128==0, K%32==0.
__global__ __launch_bounds__(256) void gemm_bf16(
    const unsigned short* __restrict__ A, const unsigned short* __restrict__ B,
    const float* __restrict__ bias, float* __restrict__ C, int M, int N, int K) {
  __shared__ unsigned short smA[128 * 32];
  __shared__ unsigned short smB[128 * 32];
  const int tid = threadIdx.x;
  const int wid = tid >> 6;
  const int lane = tid & 63;
  const int m0 = blockIdx.y * 128;
  const int n0 = blockIdx.x * 128;
  const int wr = wid >> 1, wc = wid & 1;
  f32x4 acc[4][4] = {};
  const int srow = lane >> 2;        // row within a 16-row staging issue
  const int scol = (lane & 3) * 8;   // bf16 col (8 bf16 = 16B per lane)
  const int fr = lane & 15;
  const int fk = (lane >> 4) * 8;
  for (int k0 = 0; k0 < K; k0 += 32) {
#pragma unroll
    for (int t = 0; t < 2; ++t) {
      const int r0 = wid * 32 + t * 16;
      gload_lds16(A + (size_t)(m0 + r0 + srow) * K + k0 + scol, &smA[r0 * 32]);
      gload_lds16(B + (size_t)(n0 + r0 + srow) * K + k0 + scol, &smB[r0 * 32]);
    }
    __syncthreads();
    short8 af[4], bf[4];
#pragma unroll
    for (int i = 0; i < 4; ++i) {
      af[i] = *(const short8*)&smA[(wr * 64 + i * 16 + fr) * 32 + fk];
      bf[i] = *(const short8*)&smB[(wc * 64 + i * 16 + fr) * 32 + fk];
    }
#pragma unroll
    for (int i = 0; i < 4; ++i)
#pragma unroll
      for (int j = 0; j < 4; ++j)
        acc[i][j] = __builtin_amdgcn_mfma_f32_16x16x32_bf16(af[i], bf[j], acc[i][j], 0, 0, 0);
    __syncthreads();
  }
  const int cl = lane & 15;
  const int rg = (lane >> 4) * 4;
#pragma unroll
  for (int i = 0; i < 4; ++i) {
    const int mrow0 = m0 + wr * 64 + i * 16 + rg;
#pragma unroll
    for (int j = 0; j < 4; ++j) {
      const int col = n0 + wc * 64 + j * 16 + cl;
      const float bv = bias[col];
#pragma unroll
      for (int r = 0; r < 4; ++r)
        C[(size_t)(mrow0 + r) * N + col] = acc[i][j][r] + bv;
    }
  }
}

// ---------------- mask statistics ----------------
__global__ void mask_stats1(const int* __restrict__ am, float* __restrict__ wsum,
                            float* __restrict__ svalid) {
  int n = blockIdx.x * blockDim.x + threadIdx.x;
  if (n < 1024) {
    int s = 0;
    const int* p = am + (size_t)n * 64;
    for (int w = 0; w < 64; ++w) s += p[w];
    wsum[n] = (float)s;
    svalid[n] = s > 0 ? 1.f : 0.f;
  }
}

__global__ void mask_stats2(const float* __restrict__ wsum, const float* __restrict__ svalid,
                            float* __restrict__ cnt2, float* __restrict__ secv,
                            float* __restrict__ cnt3) {
  int tid = threadIdx.x;  // 64 threads
  if (tid < 64) {
    float c = 0.f, t = 0.f;
    for (int u = 0; u < 16; ++u) { c += svalid[tid * 16 + u]; t += wsum[tid * 16 + u]; }
    cnt2[tid] = c;
    secv[tid] = t > 0.f ? 1.f : 0.f;
  }
  __syncthreads();
  if (tid < 8) {
    float c = 0.f;
    for (int s = 0; s < 8; ++s) c += secv[tid * 8 + s];
    cnt3[tid] = c;
  }
}

// ---------------- fp32 GEMM: out[m,n] = sum_k X[m,k]*W[n,k] + bias[n]*sfac(m) ------
#define BM 64
#define BN 64
#define BK 16
__global__ __launch_bounds__(256) void gemm_nt(
    const float* __restrict__ X, const float* __restrict__ W,
    const float* __restrict__ bias, const float* __restrict__ cnt,
    float* __restrict__ out, int M, int N, int K) {
  __shared__ float As[BK][BM + 4];
  __shared__ float Bs[BK][BN + 4];
  const int tid = threadIdx.x;
  const int m0 = blockIdx.y * BM;
  const int n0 = blockIdx.x * BN;
  const int tx = tid & 15, ty = tid >> 4;
  const int lr = tid >> 2;
  const int lc = (tid & 3) * 4;
  float acc[4][4];
#pragma unroll
  for (int i = 0; i < 4; ++i)
#pragma unroll
    for (int j = 0; j < 4; ++j) acc[i][j] = 0.f;
  for (int k0 = 0; k0 < K; k0 += BK) {
    float4 xa = make_float4(0.f, 0.f, 0.f, 0.f);
    if (m0 + lr < M) xa = *(const float4*)(X + (size_t)(m0 + lr) * K + k0 + lc);
    float4 wb = *(const float4*)(W + (size_t)(n0 + lr) * K + k0 + lc);
    As[lc + 0][lr] = xa.x; As[lc + 1][lr] = xa.y; As[lc + 2][lr] = xa.z; As[lc + 3][lr] = xa.w;
    Bs[lc + 0][lr] = wb.x; Bs[lc + 1][lr] = wb.y; Bs[lc + 2][lr] = wb.z; Bs[lc + 3][lr] = wb.w;
    __syncthreads();
#pragma unroll
    for (int kk = 0; kk < BK; ++kk) {
      float4 av = *(const float4*)&As[kk][ty * 4];
      float4 bv = *(const float4*)&Bs[kk][tx * 4];
      float a4[4] = {av.x, av.y, av.z, av.w};
      float b4[4] = {bv.x, bv.y, bv.z, bv.w};
#pragma unroll
      for (int i = 0; i < 4; ++i)
#pragma unroll
        for (int j = 0; j < 4; ++j) acc[i][j] += a4[i] * b4[j];
    }
    __syncthreads();
  }
#pragma unroll
  for (int i = 0; i < 4; ++i) {
    int m = m0 + ty * 4 + i;
    if (m < M) {
      float sf = 1.f;
      if (cnt) { float c = cnt[m]; sf = c / (c + 1e-10f); }
      float4 o;
      o.x = acc[i][0] + bias[n0 + tx * 4 + 0] * sf;
      o.y = acc[i][1] + bias[n0 + tx * 4 + 1] * sf;
      o.z = acc[i][2] + bias[n0 + tx * 4 + 2] * sf;
      o.w = acc[i][3] + bias[n0 + tx * 4 + 3] * sf;
      *(float4*)(out + (size_t)m * N + n0 + tx * 4) = o;
    }
  }
}

// ---------------- word-level attention (L=64), pooled output per (seq,head) ----------------
__global__ __launch_bounds__(256) void word_attn(
    const float* __restrict__ qkv, const int* __restrict__ am,
    const float* __restrict__ wsum, float* __restrict__ obar, int s0) {
  const int nl = blockIdx.x;
  const int h = blockIdx.y;
  const int n = s0 + nl;
  const int tid = threadIdx.x;
  __shared__ float qs[64][65];
  __shared__ float ks[64][65];
  __shared__ float red[64][65];
  __shared__ float abar[64];
  __shared__ float msk[64];
  const float* qb = qkv + (size_t)nl * 64 * E3 + h * DDIM;
  const float* kb = qb + EDIM;
  const float* vb = qb + 2 * EDIM;
  if (tid < 64) msk[tid] = (am[(size_t)n * 64 + tid] > 0) ? 1.f : 0.f;
  const int l = tid >> 2;
  const int mg = (tid & 3) * 16;
  float sc[16];
#pragma unroll
  for (int j = 0; j < 16; ++j) sc[j] = 0.f;
  for (int dd0 = 0; dd0 < DDIM; dd0 += 64) {
    for (int it = 0; it < 4; ++it) {
      int i4 = tid + it * 256;
      int r = i4 >> 4;
      int c = (i4 & 15) * 4;
      float4 qv4 = *(const float4*)(qb + (size_t)r * E3 + dd0 + c);
      float4 kv4 = *(const float4*)(kb + (size_t)r * E3 + dd0 + c);
      qs[r][c] = qv4.x; qs[r][c + 1] = qv4.y; qs[r][c + 2] = qv4.z; qs[r][c + 3] = qv4.w;
      ks[r][c] = kv4.x; ks[r][c + 1] = kv4.y; ks[r][c + 2] = kv4.z; ks[r][c + 3] = kv4.w;
    }
    __syncthreads();
    for (int c = 0; c < 64; ++c) {
      float qv = qs[l][c];
#pragma unroll
      for (int j = 0; j < 16; ++j) sc[j] += qv * ks[mg + j][c];
    }
    __syncthreads();
  }
  const float scale = 0.07216878364870323f;  // 1/sqrt(192)
  float mx = -1e30f;
#pragma unroll
  for (int j = 0; j < 16; ++j) {
    float s = (msk[mg + j] > 0.f) ? sc[j] * scale : -1e9f;
    sc[j] = s;
    mx = fmaxf(mx, s);
  }
  mx = fmaxf(mx, __shfl_xor(mx, 1));
  mx = fmaxf(mx, __shfl_xor(mx, 2));
  float sum = 0.f;
#pragma unroll
  for (int j = 0; j < 16; ++j) { float p = expf(sc[j] - mx); sc[j] = p; sum += p; }
  sum += __shfl_xor(sum, 1);
  sum += __shfl_xor(sum, 2);
  float den = wsum[n] + 1e-10f;
  float wl = (msk[l] > 0.f) ? (1.f / den) : 0.f;
  float inv = wl / sum;
#pragma unroll
  for (int j = 0; j < 16; ++j) red[l][mg + j] = sc[j] * inv;
  __syncthreads();
  if (tid < 64) {
    float s = 0.f;
    for (int l2 = 0; l2 < 64; ++l2) s += red[l2][tid];
    abar[tid] = s;
  }
  __syncthreads();
  if (tid < 192) {
    float acc = 0.f;
    for (int m = 0; m < 64; ++m) acc += abar[m] * vb[(size_t)m * E3 + tid];
    obar[(size_t)n * EDIM + h * DDIM + tid] = acc;
  }
}

// ---------------- small attention (L=16 or 8), pooled output ----------------
__global__ __launch_bounds__(256) void small_attn(
    const float* __restrict__ qkv, const float* __restrict__ maskv,
    const float* __restrict__ cnt, float* __restrict__ obar, int L) {
  const int n = blockIdx.x;
  const int h = blockIdx.y;
  const int tid = threadIdx.x;
  __shared__ float red[16][17];
  __shared__ float abar[16];
  const float* qb = qkv + (size_t)n * L * E3 + h * DDIM;
  const float* kb = qb + EDIM;
  const float* vb = qb + 2 * EDIM;
  const float scale = 0.07216878364870323f;
  if (tid < L * L) {
    int l = tid / L, m = tid % L;
    float s = 0.f;
    for (int dd = 0; dd < DDIM; ++dd) s += qb[(size_t)l * E3 + dd] * kb[(size_t)m * E3 + dd];
    s = (maskv[n * L + m] > 0.f) ? s * scale : -1e9f;
    float mx = s;
    for (int off = L >> 1; off > 0; off >>= 1) mx = fmaxf(mx, __shfl_xor(mx, off));
    float p = expf(s - mx);
    float sum = p;
    for (int off = L >> 1; off > 0; off >>= 1) sum += __shfl_xor(sum, off);
    float den = cnt[n] + 1e-10f;
    float wl = (maskv[n * L + l] > 0.f) ? (1.f / den) : 0.f;
    red[l][m] = p / sum * wl;
  }
  __syncthreads();
  if (tid < L) {
    float s = 0.f;
    for (int l2 = 0; l2 < L; ++l2) s += red[l2][tid];
    abar[tid] = s;
  }
  __syncthreads();
  if (tid < 192) {
    float acc = 0.f;
    for (int m = 0; m < L; ++m) acc += abar[m] * vb[(size_t)m * E3 + tid];
    obar[(size_t)n * EDIM + h * DDIM + tid] = acc;
  }
}

// ---------------- fusion head: [8,768] doc -> [8,3] ----------------
__global__ __launch_bounds__(256) void head_kernel(
    const float* __restrict__ doc, const float* __restrict__ hand,
    const float* __restrict__ bp_w, const float* __restrict__ bp_b,
    const float* __restrict__ hp_w, const float* __restrict__ hp_b,
    const float* __restrict__ gate_w, const float* __restrict__ gate_b,
    const float* __restrict__ fg, const float* __restrict__ fbv,
    const float* __restrict__ fc1_w, const float* __restrict__ fc1_b,
    const float* __restrict__ g1, const float* __restrict__ b1,
    const float* __restrict__ fc2_w, const float* __restrict__ fc2_b,
    float* __restrict__ out) {
  int b = blockIdx.x, tid = threadIdx.x;
  __shared__ float bp[256], hp[256], fz[256], hz[128];
  const float* dr = doc + (size_t)b * 768;
  float acc = bp_b[tid];
  for (int k = 0; k < 768; ++k) acc += dr[k] * bp_w[(size_t)tid * 768 + k];
  bp[tid] = acc;
  const float* hr = hand + b * 20;
  float acc2 = hp_b[tid];
  for (int k = 0; k < 20; ++k) acc2 += hr[k] * hp_w[tid * 20 + k];
  hp[tid] = acc2;
  __syncthreads();
  float g = gate_b[tid];
  for (int k = 0; k < 256; ++k) g += bp[k] * gate_w[tid * 512 + k];
  for (int k = 0; k < 256; ++k) g += hp[k] * gate_w[tid * 512 + 256 + k];
  g = 1.f / (1.f + expf(-g));
  float fu = g * bp[tid] + (1.f - g) * hp[tid];
  fz[tid] = fu;
  __syncthreads();
  float mu = 0.f;
  for (int k = 0; k < 256; ++k) mu += fz[k];
  mu /= 256.f;
  float va = 0.f;
  for (int k = 0; k < 256; ++k) { float d = fz[k] - mu; va += d * d; }
  va /= 256.f;
  float fl = (fu - mu) / sqrtf(va + 1e-5f) * fg[tid] + fbv[tid];
  __syncthreads();
  fz[tid] = fl;
  __syncthreads();
  if (tid < 128) {
    float a = fc1_b[tid];
    for (int k = 0; k < 256; ++k) a += fz[k] * fc1_w[tid * 256 + k];
    hz[tid] = fmaxf(a, 0.f);
  }
  __syncthreads();
  float mu2 = 0.f;
  for (int k = 0; k < 128; ++k) mu2 += hz[k];
  mu2 /= 128.f;
  float va2 = 0.f;
  for (int k = 0; k < 128; ++k) { float d = hz[k] - mu2; va2 += d * d; }
  va2 /= 128.f;
  __syncthreads();
  if (tid < 128) hz[tid] = (hz[tid] - mu2) / sqrtf(va2 + 1e-5f) * g1[tid] + b1[tid];
  __syncthreads();
  if (tid < 3) {
    float o = fc2_b[tid];
    for (int k = 0; k < 128; ++k) o += hz[k] * fc2_w[tid * 128 + k];
    out[b * 3 + tid] = o;
  }
}

extern "C" void kernel_launch(void* const* d_in, const int* in_sizes, int n_in,
                              void* d_out, int out_size, void* d_ws, size_t ws_size,
                              hipStream_t stream) {
  const float* we      = (const float*)d_in[0];
  const int*   am      = (const int*)d_in[1];
  const float* hand    = (const float*)d_in[2];
  const float* w_w_in  = (const float*)d_in[3];
  const float* w_b_in  = (const float*)d_in[4];
  const float* w_w_out = (const float*)d_in[5];
  const float* w_b_out = (const float*)d_in[6];
  const float* s_w_in  = (const float*)d_in[7];
  const float* s_b_in  = (const float*)d_in[8];
  const float* s_w_out = (const float*)d_in[9];
  const float* s_b_out = (const float*)d_in[10];
  const float* c_w_in  = (const float*)d_in[11];
  const float* c_b_in  = (const float*)d_in[12];
  const float* c_w_out = (const float*)d_in[13];
  const float* c_b_out = (const float*)d_in[14];
  const float* bp_w = (const float*)d_in[15];
  const float* bp_b = (const float*)d_in[16];
  const float* hp_w = (const float*)d_in[17];
  const float* hp_b = (const float*)d_in[18];
  // d_in[19..22] = fa_* (cross-attention) — output unused by the reference, skipped.
  const float* gate_w = (const float*)d_in[23];
  const float* gate_b = (const float*)d_in[24];
  const float* fus_g  = (const float*)d_in[25];
  const float* fus_b  = (const float*)d_in[26];
  const float* fc1_w  = (const float*)d_in[27];
  const float* fc1_b  = (const float*)d_in[28];
  const float* ln1_g  = (const float*)d_in[29];
  const float* ln1_b  = (const float*)d_in[30];
  const float* fc2_w  = (const float*)d_in[31];
  const float* fc2_b  = (const float*)d_in[32];
  float* out = (float*)d_out;

  // carve small buffers from the top of the workspace (byte-granular, 256B aligned)
  char* end = (char*)d_ws + ws_size;
  auto carveb = [&](size_t bytes) {
    size_t b = (bytes + 255) & ~(size_t)255;
    end -= b;
    return (void*)end;
  };
  float* obar1  = (float*)carveb(1024 * 768 * 4);
  float* sent   = (float*)carveb(1024 * 768 * 4);
  float* qkv2   = (float*)carveb(1024 * 2304 * 4);
  float* obar2  = (float*)carveb(64 * 768 * 4);
  float* sec    = (float*)carveb(64 * 768 * 4);
  float* qkv3   = (float*)carveb(64 * 2304 * 4);
  float* obar3  = (float*)carveb(8 * 768 * 4);
  float* doc    = (float*)carveb(8 * 768 * 4);
  float* wsum   = (float*)carveb(1024 * 4);
  float* svalid = (float*)carveb(1024 * 4);
  float* cnt2   = (float*)carveb(64 * 4);
  float* secv   = (float*)carveb(64 * 4);
  float* cnt3   = (float*)carveb(8 * 4);
  unsigned short* wbf = (unsigned short*)carveb((size_t)2304 * 768 * 2);

  float* qkv1 = (float*)d_ws;
  size_t avail = (size_t)(end - (char*)d_ws);
  // per chunk of cs sequences: qkv1 fp32 (cs*64*2304*4) + xbf bf16 (cs*64*768*2)
  int cs = 1024;
  while (cs > 16 && (size_t)cs * (64 * 2304 * 4 + 64 * 768 * 2) > avail) cs >>= 1;
  unsigned short* xbf = (unsigned short*)(qkv1 + (size_t)cs * 64 * 2304);

  // weight conversion + mask statistics
  f2bf<<<432, 256, 0, stream>>>(w_w_in, wbf, (size_t)2304 * 768);
  mask_stats1<<<4, 256, 0, stream>>>(am, wsum, svalid);
  mask_stats2<<<1, 64, 0, stream>>>(wsum, svalid, cnt2, secv, cnt3);

  for (int s0 = 0; s0 < 1024; s0 += cs) {
    int c = (1024 - s0 < cs) ? (1024 - s0) : cs;
    size_t nel = (size_t)c * 64 * 768;
    f2bf<<<2048, 256, 0, stream>>>(we + (size_t)s0 * 64 * 768, xbf, nel);
    gemm_bf16<<<dim3(2304 / 128, c * 64 / 128), 256, 0, stream>>>(
        xbf, wbf, w_b_in, qkv1, c * 64, 2304, 768);
    word_attn<<<dim3(c, 4), 256, 0, stream>>>(qkv1, am, wsum, obar1, s0);
  }
  // sent = obar1 @ w_out.T + b_out * sfac
  gemm_nt<<<dim3(12, 16), 256, 0, stream>>>(obar1, w_w_out, w_b_out, wsum, sent, 1024, 768, 768);
  // sentence level
  gemm_nt<<<dim3(36, 16), 256, 0, stream>>>(sent, s_w_in, s_b_in, nullptr, qkv2, 1024, 2304, 768);
  small_attn<<<dim3(64, 4), 256, 0, stream>>>(qkv2, svalid, cnt2, obar2, 16);
  gemm_nt<<<dim3(12, 1), 256, 0, stream>>>(obar2, s_w_out, s_b_out, cnt2, sec, 64, 768, 768);
  // section level
  gemm_nt<<<dim3(36, 1), 256, 0, stream>>>(sec, c_w_in, c_b_in, nullptr, qkv3, 64, 2304, 768);
  small_attn<<<dim3(8, 4), 256, 0, stream>>>(qkv3, secv, cnt3, obar3, 8);
  gemm_nt<<<dim3(12, 1), 256, 0, stream>>>(obar3, c_w_out, c_b_out, cnt3, doc, 8, 768, 768);
  // fusion head
  head_kernel<<<8, 256, 0, stream>>>(doc, hand, bp_w, bp_b, hp_w, hp_b, gate_w, gate_b,
                                     fus_g, fus_b, fc1_w, fc1_b, ln1_g, ln1_b, fc2_w, fc2_b, out);
}

// Round 3
// 845.717 us; speedup vs baseline: 4.3935x; 1.3347x over previous
//
#include <hip/hip_runtime.h>
#include <math.h>

#define EDIM 768
#define E3 2304
#define XLD 776  // 768 + 8 bf16 pad (keeps 16B row alignment, breaks bank alias)
#define QLD 200  // 192 + 8 pad

typedef __attribute__((ext_vector_type(8))) short short8;
typedef __attribute__((ext_vector_type(8))) unsigned short ushort8;
typedef __attribute__((ext_vector_type(4))) float f32x4;

__device__ inline unsigned short f2b_rne(float f) {
  unsigned int u = __builtin_bit_cast(unsigned int, f);
  u = (u + 0x7fffu + ((u >> 16) & 1u)) >> 16;
  return (unsigned short)u;
}
__device__ inline float b2f(unsigned short u) {
  unsigned int x = ((unsigned int)u) << 16;
  return __builtin_bit_cast(float, x);
}

// ---------------- fp32 -> bf16 conversion ----------------
__global__ __launch_bounds__(256) void f2bf(const float* __restrict__ in,
                                            unsigned short* __restrict__ out, size_t n) {
  size_t i = ((size_t)blockIdx.x * blockDim.x + threadIdx.x) * 8;
  size_t stride = (size_t)gridDim.x * blockDim.x * 8;
  for (; i < n; i += stride) {
    float4 a = *(const float4*)(in + i);
    float4 b = *(const float4*)(in + i + 4);
    ushort8 o;
    o[0] = f2b_rne(a.x); o[1] = f2b_rne(a.y); o[2] = f2b_rne(a.z); o[3] = f2b_rne(a.w);
    o[4] = f2b_rne(b.x); o[5] = f2b_rne(b.y); o[6] = f2b_rne(b.z); o[7] = f2b_rne(b.w);
    *(ushort8*)(out + i) = o;
  }
}

// ---------------- mask statistics ----------------
__global__ void mask_stats1(const int* __restrict__ am, float* __restrict__ wsum,
                            float* __restrict__ svalid) {
  int n = blockIdx.x * blockDim.x + threadIdx.x;
  if (n < 1024) {
    int s = 0;
    const int* p = am + (size_t)n * 64;
    for (int w = 0; w < 64; ++w) s += p[w];
    wsum[n] = (float)s;
    svalid[n] = s > 0 ? 1.f : 0.f;
  }
}

__global__ void mask_stats2(const float* __restrict__ wsum, const float* __restrict__ svalid,
                            float* __restrict__ cnt2, float* __restrict__ secv,
                            float* __restrict__ cnt3) {
  int tid = threadIdx.x;  // 64 threads
  if (tid < 64) {
    float c = 0.f, t = 0.f;
    for (int u = 0; u < 16; ++u) { c += svalid[tid * 16 + u]; t += wsum[tid * 16 + u]; }
    cnt2[tid] = c;
    secv[tid] = t > 0.f ? 1.f : 0.f;
  }
  __syncthreads();
  if (tid < 8) {
    float c = 0.f;
    for (int s = 0; s < 8; ++s) c += secv[tid * 8 + s];
    cnt3[tid] = c;
  }
}

// ---------------- fused word-level attention ----------------
// One block per sentence. X (64x768) -> bf16 LDS. Per head: Q,K = X@W^T via MFMA
// (W streamed L2->regs, waves N-sliced), repack bf16 -> LDS, S = QK^T via MFMA,
// in-register masked softmax + mean-pool weights -> abar; finally
// xbar[n,h,:] = sum_m abar[h][m] * X[m,:]  (V-projection deferred to a GEMM).
__global__ __launch_bounds__(256, 1) void fused_word(
    const float* __restrict__ we, const int* __restrict__ am,
    const unsigned short* __restrict__ wqk, const float* __restrict__ b_in,
    const float* __restrict__ wsum, float* __restrict__ xbar) {
  __shared__ unsigned short Xs[64 * XLD];
  __shared__ unsigned short Qs[64 * QLD];
  __shared__ unsigned short Ks[64 * QLD];
  __shared__ float abars[4][64];
  __shared__ float abar_all[4][64];
  __shared__ float msk[64];
  const int n = blockIdx.x;
  const int tid = threadIdx.x;
  const int wid = tid >> 6;
  const int lane = tid & 63;
  const float* xg = we + (size_t)n * 64 * 768;

  // stage X -> bf16 LDS
  for (int it = 0; it < 24; ++it) {
    int idx = tid + it * 256;  // 0..6143
    int row = idx / 96;
    int c8 = (idx % 96) * 8;
    float4 a = *(const float4*)(xg + row * 768 + c8);
    float4 b = *(const float4*)(xg + row * 768 + c8 + 4);
    ushort8 o;
    o[0] = f2b_rne(a.x); o[1] = f2b_rne(a.y); o[2] = f2b_rne(a.z); o[3] = f2b_rne(a.w);
    o[4] = f2b_rne(b.x); o[5] = f2b_rne(b.y); o[6] = f2b_rne(b.z); o[7] = f2b_rne(b.w);
    *(ushort8*)&Xs[row * XLD + c8] = o;
  }
  if (tid < 64) msk[tid] = (am[(size_t)n * 64 + tid] > 0) ? 1.f : 0.f;
  __syncthreads();

  const int fr = lane & 15;
  const int fk = (lane >> 4) * 8;
  const float den = wsum[n] + 1e-10f;
  const float scale = 0.07216878364870323f;  // 1/sqrt(192)

  for (int h = 0; h < 4; ++h) {
    // ---- phase 1: wave 0,1 -> Q_h cols [0,96),[96,192); wave 2,3 -> K_h same
    const int isK = wid >> 1;
    const int half = wid & 1;
    const int base_row = (isK ? 768 : 0) + h * 192 + half * 96;
    const unsigned short* bp0 = wqk + (size_t)base_row * 768;
    f32x4 acc[4][6] = {};
    short8 bcur[6];
#pragma unroll
    for (int j = 0; j < 6; ++j)
      bcur[j] = *(const short8*)(bp0 + (size_t)(j * 16 + fr) * 768 + fk);
    for (int k0 = 0; k0 < 768; k0 += 32) {
      const int kn = (k0 + 32 < 768) ? k0 + 32 : 0;  // last prefetch discarded
      short8 bnext[6];
#pragma unroll
      for (int j = 0; j < 6; ++j)
        bnext[j] = *(const short8*)(bp0 + (size_t)(j * 16 + fr) * 768 + kn + fk);
      short8 af[4];
#pragma unroll
      for (int i = 0; i < 4; ++i)
        af[i] = *(const short8*)&Xs[(i * 16 + fr) * XLD + k0 + fk];
#pragma unroll
      for (int i = 0; i < 4; ++i)
#pragma unroll
        for (int j = 0; j < 6; ++j)
          acc[i][j] = __builtin_amdgcn_mfma_f32_16x16x32_bf16(af[i], bcur[j], acc[i][j], 0, 0, 0);
#pragma unroll
      for (int j = 0; j < 6; ++j) bcur[j] = bnext[j];
    }
    // bias add + repack to LDS bf16 (C-frag: col=lane&15, row=(lane>>4)*4+r)
    unsigned short* dst = isK ? Ks : Qs;
    const int cbase = half * 96;
#pragma unroll
    for (int j = 0; j < 6; ++j) {
      float bj = b_in[base_row + j * 16 + fr];
      int col = cbase + j * 16 + fr;
#pragma unroll
      for (int i = 0; i < 4; ++i) {
        int r0 = i * 16 + (lane >> 4) * 4;
#pragma unroll
        for (int r = 0; r < 4; ++r)
          dst[(r0 + r) * QLD + col] = f2b_rne(acc[i][j][r] + bj);
      }
    }
    __syncthreads();

    // ---- phase 2: S rows [wid*16, wid*16+16) x all 64 cols, contraction 192
    f32x4 sfr[4] = {};
#pragma unroll
    for (int ks = 0; ks < 6; ++ks) {
      short8 aq = *(const short8*)&Qs[(wid * 16 + fr) * QLD + ks * 32 + fk];
#pragma unroll
      for (int j = 0; j < 4; ++j) {
        short8 bk8 = *(const short8*)&Ks[(j * 16 + fr) * QLD + ks * 32 + fk];
        sfr[j] = __builtin_amdgcn_mfma_f32_16x16x32_bf16(aq, bk8, sfr[j], 0, 0, 0);
      }
    }

    // ---- phase 3: masked softmax + pooling weights -> column sums (abar)
    float mcol[4];
#pragma unroll
    for (int j = 0; j < 4; ++j) mcol[j] = msk[j * 16 + fr];
    float p[4][4];
#pragma unroll
    for (int r = 0; r < 4; ++r) {
      float s[4];
      float mx = -1e30f;
#pragma unroll
      for (int j = 0; j < 4; ++j) {
        float v = mcol[j] > 0.f ? sfr[j][r] * scale : -1e9f;
        s[j] = v;
        mx = fmaxf(mx, v);
      }
      mx = fmaxf(mx, __shfl_xor(mx, 1));
      mx = fmaxf(mx, __shfl_xor(mx, 2));
      mx = fmaxf(mx, __shfl_xor(mx, 4));
      mx = fmaxf(mx, __shfl_xor(mx, 8));
      float sum = 0.f;
#pragma unroll
      for (int j = 0; j < 4; ++j) { s[j] = expf(s[j] - mx); sum += s[j]; }
      sum += __shfl_xor(sum, 1);
      sum += __shfl_xor(sum, 2);
      sum += __shfl_xor(sum, 4);
      sum += __shfl_xor(sum, 8);
      float wrow = msk[wid * 16 + (lane >> 4) * 4 + r] / den;
      float f = wrow / sum;
#pragma unroll
      for (int j = 0; j < 4; ++j) p[j][r] = s[j] * f;
    }
#pragma unroll
    for (int j = 0; j < 4; ++j) {
      float cs = p[j][0] + p[j][1] + p[j][2] + p[j][3];
      cs += __shfl_xor(cs, 16);
      cs += __shfl_xor(cs, 32);
      if (lane < 16) abars[wid][j * 16 + lane] = cs;
    }
    __syncthreads();
    if (tid < 64)
      abar_all[h][tid] = abars[0][tid] + abars[1][tid] + abars[2][tid] + abars[3][tid];
    __syncthreads();
  }

  // ---- phase 4: xbar[h][d] = sum_m abar[h][m] * X[m][d]
  float a4[4][3] = {};
  for (int m = 0; m < 64; ++m) {
    float ab0 = abar_all[0][m], ab1 = abar_all[1][m];
    float ab2 = abar_all[2][m], ab3 = abar_all[3][m];
#pragma unroll
    for (int u = 0; u < 3; ++u) {
      float x = b2f(Xs[m * XLD + u * 256 + tid]);
      a4[0][u] += ab0 * x;
      a4[1][u] += ab1 * x;
      a4[2][u] += ab2 * x;
      a4[3][u] += ab3 * x;
    }
  }
  float* xo = xbar + (size_t)n * 4 * 768;
#pragma unroll
  for (int hh = 0; hh < 4; ++hh)
#pragma unroll
    for (int u = 0; u < 3; ++u)
      xo[hh * 768 + u * 256 + tid] = a4[hh][u];
}

// ---------------- fp32 GEMM: out[m,n] = sum_k X[m*lda+k]*W[n,k] + bias[n]*sfac(m) ------
#define BM 64
#define BN 64
#define BK 16
__global__ __launch_bounds__(256) void gemm_nt(
    const float* __restrict__ X, const float* __restrict__ W,
    const float* __restrict__ bias, const float* __restrict__ cnt,
    float* __restrict__ out, int M, int N, int K, int lda, int ldc) {
  __shared__ float As[BK][BM + 4];
  __shared__ float Bs[BK][BN + 4];
  const int tid = threadIdx.x;
  const int m0 = blockIdx.y * BM;
  const int n0 = blockIdx.x * BN;
  const int tx = tid & 15, ty = tid >> 4;
  const int lr = tid >> 2;
  const int lc = (tid & 3) * 4;
  float acc[4][4];
#pragma unroll
  for (int i = 0; i < 4; ++i)
#pragma unroll
    for (int j = 0; j < 4; ++j) acc[i][j] = 0.f;
  for (int k0 = 0; k0 < K; k0 += BK) {
    float4 xa = make_float4(0.f, 0.f, 0.f, 0.f);
    if (m0 + lr < M) xa = *(const float4*)(X + (size_t)(m0 + lr) * lda + k0 + lc);
    float4 wb = *(const float4*)(W + (size_t)(n0 + lr) * K + k0 + lc);
    As[lc + 0][lr] = xa.x; As[lc + 1][lr] = xa.y; As[lc + 2][lr] = xa.z; As[lc + 3][lr] = xa.w;
    Bs[lc + 0][lr] = wb.x; Bs[lc + 1][lr] = wb.y; Bs[lc + 2][lr] = wb.z; Bs[lc + 3][lr] = wb.w;
    __syncthreads();
#pragma unroll
    for (int kk = 0; kk < BK; ++kk) {
      float4 av = *(const float4*)&As[kk][ty * 4];
      float4 bv = *(const float4*)&Bs[kk][tx * 4];
      float a4[4] = {av.x, av.y, av.z, av.w};
      float b4[4] = {bv.x, bv.y, bv.z, bv.w};
#pragma unroll
      for (int i = 0; i < 4; ++i)
#pragma unroll
        for (int j = 0; j < 4; ++j) acc[i][j] += a4[i] * b4[j];
    }
    __syncthreads();
  }
#pragma unroll
  for (int i = 0; i < 4; ++i) {
    int m = m0 + ty * 4 + i;
    if (m < M) {
      float sf = 1.f;
      if (cnt) { float c = cnt[m]; sf = c / (c + 1e-10f); }
      float4 o;
      o.x = acc[i][0] + bias[n0 + tx * 4 + 0] * sf;
      o.y = acc[i][1] + bias[n0 + tx * 4 + 1] * sf;
      o.z = acc[i][2] + bias[n0 + tx * 4 + 2] * sf;
      o.w = acc[i][3] + bias[n0 + tx * 4 + 3] * sf;
      *(float4*)(out + (size_t)m * ldc + n0 + tx * 4) = o;
    }
  }
}

// ---------------- small attention (L=16 or 8), pooled output ----------------
__global__ __launch_bounds__(256) void small_attn(
    const float* __restrict__ qkv, const float* __restrict__ maskv,
    const float* __restrict__ cnt, float* __restrict__ obar, int L) {
  const int n = blockIdx.x;
  const int h = blockIdx.y;
  const int tid = threadIdx.x;
  __shared__ float red[16][17];
  __shared__ float abar[16];
  const float* qb = qkv + (size_t)n * L * E3 + h * 192;
  const float* kb = qb + EDIM;
  const float* vb = qb + 2 * EDIM;
  const float scale = 0.07216878364870323f;
  if (tid < L * L) {
    int l = tid / L, m = tid % L;
    float s = 0.f;
    for (int dd = 0; dd < 192; ++dd) s += qb[(size_t)l * E3 + dd] * kb[(size_t)m * E3 + dd];
    s = (maskv[n * L + m] > 0.f) ? s * scale : -1e9f;
    float mx = s;
    for (int off = L >> 1; off > 0; off >>= 1) mx = fmaxf(mx, __shfl_xor(mx, off));
    float p = expf(s - mx);
    float sum = p;
    for (int off = L >> 1; off > 0; off >>= 1) sum += __shfl_xor(sum, off);
    float dn = cnt[n] + 1e-10f;
    float wl = (maskv[n * L + l] > 0.f) ? (1.f / dn) : 0.f;
    red[l][m] = p / sum * wl;
  }
  __syncthreads();
  if (tid < L) {
    float s = 0.f;
    for (int l2 = 0; l2 < L; ++l2) s += red[l2][tid];
    abar[tid] = s;
  }
  __syncthreads();
  if (tid < 192) {
    float acc = 0.f;
    for (int m = 0; m < L; ++m) acc += abar[m] * vb[(size_t)m * E3 + tid];
    obar[(size_t)n * EDIM + h * 192 + tid] = acc;
  }
}

// ---------------- fusion head: [8,768] doc -> [8,3] ----------------
__global__ __launch_bounds__(256) void head_kernel(
    const float* __restrict__ doc, const float* __restrict__ hand,
    const float* __restrict__ bp_w, const float* __restrict__ bp_b,
    const float* __restrict__ hp_w, const float* __restrict__ hp_b,
    const float* __restrict__ gate_w, const float* __restrict__ gate_b,
    const float* __restrict__ fg, const float* __restrict__ fbv,
    const float* __restrict__ fc1_w, const float* __restrict__ fc1_b,
    const float* __restrict__ g1, const float* __restrict__ b1,
    const float* __restrict__ fc2_w, const float* __restrict__ fc2_b,
    float* __restrict__ out) {
  int b = blockIdx.x, tid = threadIdx.x;
  __shared__ float bp[256], hp[256], fz[256], hz[128];
  const float* dr = doc + (size_t)b * 768;
  float acc = bp_b[tid];
  for (int k = 0; k < 768; ++k) acc += dr[k] * bp_w[(size_t)tid * 768 + k];
  bp[tid] = acc;
  const float* hr = hand + b * 20;
  float acc2 = hp_b[tid];
  for (int k = 0; k < 20; ++k) acc2 += hr[k] * hp_w[tid * 20 + k];
  hp[tid] = acc2;
  __syncthreads();
  float g = gate_b[tid];
  for (int k = 0; k < 256; ++k) g += bp[k] * gate_w[tid * 512 + k];
  for (int k = 0; k < 256; ++k) g += hp[k] * gate_w[tid * 512 + 256 + k];
  g = 1.f / (1.f + expf(-g));
  float fu = g * bp[tid] + (1.f - g) * hp[tid];
  fz[tid] = fu;
  __syncthreads();
  float mu = 0.f;
  for (int k = 0; k < 256; ++k) mu += fz[k];
  mu /= 256.f;
  float va = 0.f;
  for (int k = 0; k < 256; ++k) { float d = fz[k] - mu; va += d * d; }
  va /= 256.f;
  float fl = (fu - mu) / sqrtf(va + 1e-5f) * fg[tid] + fbv[tid];
  __syncthreads();
  fz[tid] = fl;
  __syncthreads();
  if (tid < 128) {
    float a = fc1_b[tid];
    for (int k = 0; k < 256; ++k) a += fz[k] * fc1_w[tid * 256 + k];
    hz[tid] = fmaxf(a, 0.f);
  }
  __syncthreads();
  float mu2 = 0.f;
  for (int k = 0; k < 128; ++k) mu2 += hz[k];
  mu2 /= 128.f;
  float va2 = 0.f;
  for (int k = 0; k < 128; ++k) { float d = hz[k] - mu2; va2 += d * d; }
  va2 /= 128.f;
  __syncthreads();
  if (tid < 128) hz[tid] = (hz[tid] - mu2) / sqrtf(va2 + 1e-5f) * g1[tid] + b1[tid];
  __syncthreads();
  if (tid < 3) {
    float o = fc2_b[tid];
    for (int k = 0; k < 128; ++k) o += hz[k] * fc2_w[tid * 128 + k];
    out[b * 3 + tid] = o;
  }
}

extern "C" void kernel_launch(void* const* d_in, const int* in_sizes, int n_in,
                              void* d_out, int out_size, void* d_ws, size_t ws_size,
                              hipStream_t stream) {
  const float* we      = (const float*)d_in[0];
  const int*   am      = (const int*)d_in[1];
  const float* hand    = (const float*)d_in[2];
  const float* w_w_in  = (const float*)d_in[3];
  const float* w_b_in  = (const float*)d_in[4];
  const float* w_w_out = (const float*)d_in[5];
  const float* w_b_out = (const float*)d_in[6];
  const float* s_w_in  = (const float*)d_in[7];
  const float* s_b_in  = (const float*)d_in[8];
  const float* s_w_out = (const float*)d_in[9];
  const float* s_b_out = (const float*)d_in[10];
  const float* c_w_in  = (const float*)d_in[11];
  const float* c_b_in  = (const float*)d_in[12];
  const float* c_w_out = (const float*)d_in[13];
  const float* c_b_out = (const float*)d_in[14];
  const float* bp_w = (const float*)d_in[15];
  const float* bp_b = (const float*)d_in[16];
  const float* hp_w = (const float*)d_in[17];
  const float* hp_b = (const float*)d_in[18];
  // d_in[19..22] = fa_* (cross-attention) — output unused by the reference, skipped.
  const float* gate_w = (const float*)d_in[23];
  const float* gate_b = (const float*)d_in[24];
  const float* fus_g  = (const float*)d_in[25];
  const float* fus_b  = (const float*)d_in[26];
  const float* fc1_w  = (const float*)d_in[27];
  const float* fc1_b  = (const float*)d_in[28];
  const float* ln1_g  = (const float*)d_in[29];
  const float* ln1_b  = (const float*)d_in[30];
  const float* fc2_w  = (const float*)d_in[31];
  const float* fc2_b  = (const float*)d_in[32];
  float* out = (float*)d_out;

  // carve buffers from the top of the workspace
  char* end = (char*)d_ws + ws_size;
  auto carveb = [&](size_t bytes) {
    size_t b = (bytes + 255) & ~(size_t)255;
    end -= b;
    return (void*)end;
  };
  float* obar1  = (float*)carveb(1024 * 768 * 4);
  float* sent   = (float*)carveb(1024 * 768 * 4);
  float* qkv2   = (float*)carveb(1024 * 2304 * 4);
  float* obar2  = (float*)carveb(64 * 768 * 4);
  float* sec    = (float*)carveb(64 * 768 * 4);
  float* qkv3   = (float*)carveb(64 * 2304 * 4);
  float* obar3  = (float*)carveb(8 * 768 * 4);
  float* doc    = (float*)carveb(8 * 768 * 4);
  float* wsum   = (float*)carveb(1024 * 4);
  float* svalid = (float*)carveb(1024 * 4);
  float* cnt2   = (float*)carveb(64 * 4);
  float* secv   = (float*)carveb(64 * 4);
  float* cnt3   = (float*)carveb(8 * 4);
  unsigned short* wqk = (unsigned short*)carveb((size_t)1536 * 768 * 2);
  float* xbar   = (float*)carveb((size_t)1024 * 4 * 768 * 4);

  // prep: W_qk -> bf16, mask stats
  f2bf<<<576, 256, 0, stream>>>(w_w_in, wqk, (size_t)1536 * 768);
  mask_stats1<<<4, 256, 0, stream>>>(am, wsum, svalid);
  mask_stats2<<<1, 64, 0, stream>>>(wsum, svalid, cnt2, secv, cnt3);

  // word level: fused QK-attention -> pooled xbar [1024][4][768]
  fused_word<<<1024, 256, 0, stream>>>(we, am, wqk, w_b_in, wsum, xbar);
  // obar1[n, h*192:(h+1)*192] = xbar[n,h,:] @ Wv_h^T + bv_h * sfac
  for (int h = 0; h < 4; ++h)
    gemm_nt<<<dim3(3, 16), 256, 0, stream>>>(
        xbar + h * 768, w_w_in + (size_t)(1536 + h * 192) * 768, w_b_in + 1536 + h * 192,
        wsum, obar1 + h * 192, 1024, 192, 768, 3072, 768);
  // sent = obar1 @ w_out^T + b_out * sfac
  gemm_nt<<<dim3(12, 16), 256, 0, stream>>>(obar1, w_w_out, w_b_out, wsum, sent,
                                            1024, 768, 768, 768, 768);
  // sentence level
  gemm_nt<<<dim3(36, 16), 256, 0, stream>>>(sent, s_w_in, s_b_in, nullptr, qkv2,
                                            1024, 2304, 768, 768, 2304);
  small_attn<<<dim3(64, 4), 256, 0, stream>>>(qkv2, svalid, cnt2, obar2, 16);
  gemm_nt<<<dim3(12, 1), 256, 0, stream>>>(obar2, s_w_out, s_b_out, cnt2, sec,
                                           64, 768, 768, 768, 768);
  // section level
  gemm_nt<<<dim3(36, 1), 256, 0, stream>>>(sec, c_w_in, c_b_in, nullptr, qkv3,
                                           64, 2304, 768, 768, 2304);
  small_attn<<<dim3(8, 4), 256, 0, stream>>>(qkv3, secv, cnt3, obar3, 8);
  gemm_nt<<<dim3(12, 1), 256, 0, stream>>>(obar3, c_w_out, c_b_out, cnt3, doc,
                                           8, 768, 768, 768, 768);
  // fusion head
  head_kernel<<<8, 256, 0, stream>>>(doc, hand, bp_w, bp_b, hp_w, hp_b, gate_w, gate_b,
                                     fus_g, fus_b, fc1_w, fc1_b, ln1_g, ln1_b, fc2_w, fc2_b, out);
}

// Round 4
// 818.452 us; speedup vs baseline: 4.5398x; 1.0333x over previous
//
#include <hip/hip_runtime.h>
#include <math.h>

#define EDIM 768
#define E3 2304
#define QLD 200  // 192 + 8 bf16 pad

typedef __attribute__((ext_vector_type(8))) short short8;
typedef __attribute__((ext_vector_type(8))) unsigned short ushort8;
typedef __attribute__((ext_vector_type(4))) float f32x4;

__device__ inline void gload_lds16(const void* g, void* l) {
  __builtin_amdgcn_global_load_lds((const __attribute__((address_space(1))) void*)g,
                                   (__attribute__((address_space(3))) void*)l, 16, 0, 0);
}

__device__ inline unsigned short f2b_rne(float f) {
  unsigned int u = __builtin_bit_cast(unsigned int, f);
  u = (u + 0x7fffu + ((u >> 16) & 1u)) >> 16;
  return (unsigned short)u;
}
__device__ inline float b2f(unsigned short u) {
  unsigned int x = ((unsigned int)u) << 16;
  return __builtin_bit_cast(float, x);
}

// ---------------- fp32 -> bf16 conversion ----------------
__global__ __launch_bounds__(256) void f2bf(const float* __restrict__ in,
                                            unsigned short* __restrict__ out, size_t n) {
  size_t i = ((size_t)blockIdx.x * blockDim.x + threadIdx.x) * 8;
  size_t stride = (size_t)gridDim.x * blockDim.x * 8;
  for (; i < n; i += stride) {
    float4 a = *(const float4*)(in + i);
    float4 b = *(const float4*)(in + i + 4);
    ushort8 o;
    o[0] = f2b_rne(a.x); o[1] = f2b_rne(a.y); o[2] = f2b_rne(a.z); o[3] = f2b_rne(a.w);
    o[4] = f2b_rne(b.x); o[5] = f2b_rne(b.y); o[6] = f2b_rne(b.z); o[7] = f2b_rne(b.w);
    *(ushort8*)(out + i) = o;
  }
}

// ---------------- mask statistics ----------------
__global__ void mask_stats1(const int* __restrict__ am, float* __restrict__ wsum,
                            float* __restrict__ svalid) {
  int n = blockIdx.x * blockDim.x + threadIdx.x;
  if (n < 1024) {
    int s = 0;
    const int* p = am + (size_t)n * 64;
    for (int w = 0; w < 64; ++w) s += p[w];
    wsum[n] = (float)s;
    svalid[n] = s > 0 ? 1.f : 0.f;
  }
}

__global__ void mask_stats2(const float* __restrict__ wsum, const float* __restrict__ svalid,
                            float* __restrict__ cnt2, float* __restrict__ secv,
                            float* __restrict__ cnt3) {
  int tid = threadIdx.x;  // 64 threads
  if (tid < 64) {
    float c = 0.f, t = 0.f;
    for (int u = 0; u < 16; ++u) { c += svalid[tid * 16 + u]; t += wsum[tid * 16 + u]; }
    cnt2[tid] = c;
    secv[tid] = t > 0.f ? 1.f : 0.f;
  }
  __syncthreads();
  if (tid < 8) {
    float c = 0.f;
    for (int s = 0; s < 8; ++s) c += secv[tid * 8 + s];
    cnt3[tid] = c;
  }
}

// ---------------- fused word-level attention (occupancy-tuned) ----------------
// One block per sentence, X pre-converted to bf16 in global (xbf). Per head:
// Q,K = X@W^T via MFMA (W + X fragments streamed from L2, 1-step prefetch),
// repack bf16 -> LDS, S = QK^T via MFMA, in-register masked softmax + pooling
// weights -> abar. Finally xbar[h] = abar[h] @ X (from xbf). LDS ~53.5 KB ->
// 2 blocks/CU; launch_bounds(256,2) caps VGPR at 256 -> 2 waves/SIMD.
__global__ __launch_bounds__(256, 2) void fused_word(
    const unsigned short* __restrict__ xbf, const int* __restrict__ am,
    const unsigned short* __restrict__ wqk, const float* __restrict__ b_in,
    const float* __restrict__ wsum, float* __restrict__ xbar, int s0) {
  __shared__ unsigned short Qs[64 * QLD];
  __shared__ unsigned short Ks[64 * QLD];
  __shared__ float abars[4][64];
  __shared__ float abar_all[4][64];
  __shared__ float msk[64];
  const int nl = blockIdx.x;
  const int n = s0 + nl;
  const int tid = threadIdx.x;
  const int wid = tid >> 6;
  const int lane = tid & 63;
  const unsigned short* xg = xbf + (size_t)nl * 64 * 768;

  if (tid < 64) msk[tid] = (am[(size_t)n * 64 + tid] > 0) ? 1.f : 0.f;

  const int fr = lane & 15;
  const int fk = (lane >> 4) * 8;
  const float den = wsum[n] + 1e-10f;
  const float scale = 0.07216878364870323f;  // 1/sqrt(192)

  for (int h = 0; h < 4; ++h) {
    // ---- phase 1: wave 0,1 -> Q_h cols [0,96),[96,192); wave 2,3 -> K_h same
    const int isK = wid >> 1;
    const int half = wid & 1;
    const int base_row = (isK ? 768 : 0) + h * 192 + half * 96;
    const unsigned short* bp0 = wqk + (size_t)base_row * 768;
    f32x4 acc[4][6] = {};
    short8 bcur[6], acur[4];
#pragma unroll
    for (int j = 0; j < 6; ++j)
      bcur[j] = *(const short8*)(bp0 + (size_t)(j * 16 + fr) * 768 + fk);
#pragma unroll
    for (int i = 0; i < 4; ++i)
      acur[i] = *(const short8*)(xg + (size_t)(i * 16 + fr) * 768 + fk);
    for (int k0 = 0; k0 < 768; k0 += 32) {
      const int kn = (k0 + 32 < 768) ? k0 + 32 : 0;  // last prefetch discarded
      short8 bnext[6], anext[4];
#pragma unroll
      for (int j = 0; j < 6; ++j)
        bnext[j] = *(const short8*)(bp0 + (size_t)(j * 16 + fr) * 768 + kn + fk);
#pragma unroll
      for (int i = 0; i < 4; ++i)
        anext[i] = *(const short8*)(xg + (size_t)(i * 16 + fr) * 768 + kn + fk);
#pragma unroll
      for (int i = 0; i < 4; ++i)
#pragma unroll
        for (int j = 0; j < 6; ++j)
          acc[i][j] = __builtin_amdgcn_mfma_f32_16x16x32_bf16(acur[i], bcur[j], acc[i][j], 0, 0, 0);
#pragma unroll
      for (int j = 0; j < 6; ++j) bcur[j] = bnext[j];
#pragma unroll
      for (int i = 0; i < 4; ++i) acur[i] = anext[i];
    }
    // bias add + repack to LDS bf16 (C-frag: col=lane&15, row=(lane>>4)*4+r)
    unsigned short* dst = isK ? Ks : Qs;
    const int cbase = half * 96;
#pragma unroll
    for (int j = 0; j < 6; ++j) {
      float bj = b_in[base_row + j * 16 + fr];
      int col = cbase + j * 16 + fr;
#pragma unroll
      for (int i = 0; i < 4; ++i) {
        int r0 = i * 16 + (lane >> 4) * 4;
#pragma unroll
        for (int r = 0; r < 4; ++r)
          dst[(r0 + r) * QLD + col] = f2b_rne(acc[i][j][r] + bj);
      }
    }
    __syncthreads();

    // ---- phase 2: S rows [wid*16, wid*16+16) x all 64 cols, contraction 192
    f32x4 sfr[4] = {};
#pragma unroll
    for (int ks = 0; ks < 6; ++ks) {
      short8 aq = *(const short8*)&Qs[(wid * 16 + fr) * QLD + ks * 32 + fk];
#pragma unroll
      for (int j = 0; j < 4; ++j) {
        short8 bk8 = *(const short8*)&Ks[(j * 16 + fr) * QLD + ks * 32 + fk];
        sfr[j] = __builtin_amdgcn_mfma_f32_16x16x32_bf16(aq, bk8, sfr[j], 0, 0, 0);
      }
    }

    // ---- phase 3: masked softmax + pooling weights -> column sums (abar)
    float mcol[4];
#pragma unroll
    for (int j = 0; j < 4; ++j) mcol[j] = msk[j * 16 + fr];
    float p[4][4];
#pragma unroll
    for (int r = 0; r < 4; ++r) {
      float s[4];
      float mx = -1e30f;
#pragma unroll
      for (int j = 0; j < 4; ++j) {
        float v = mcol[j] > 0.f ? sfr[j][r] * scale : -1e9f;
        s[j] = v;
        mx = fmaxf(mx, v);
      }
      mx = fmaxf(mx, __shfl_xor(mx, 1));
      mx = fmaxf(mx, __shfl_xor(mx, 2));
      mx = fmaxf(mx, __shfl_xor(mx, 4));
      mx = fmaxf(mx, __shfl_xor(mx, 8));
      float sum = 0.f;
#pragma unroll
      for (int j = 0; j < 4; ++j) { s[j] = expf(s[j] - mx); sum += s[j]; }
      sum += __shfl_xor(sum, 1);
      sum += __shfl_xor(sum, 2);
      sum += __shfl_xor(sum, 4);
      sum += __shfl_xor(sum, 8);
      float wrow = msk[wid * 16 + (lane >> 4) * 4 + r] / den;
      float f = wrow / sum;
#pragma unroll
      for (int j = 0; j < 4; ++j) p[j][r] = s[j] * f;
    }
#pragma unroll
    for (int j = 0; j < 4; ++j) {
      float cs = p[j][0] + p[j][1] + p[j][2] + p[j][3];
      cs += __shfl_xor(cs, 16);
      cs += __shfl_xor(cs, 32);
      if (lane < 16) abars[wid][j * 16 + lane] = cs;
    }
    __syncthreads();
    if (tid < 64)
      abar_all[h][tid] = abars[0][tid] + abars[1][tid] + abars[2][tid] + abars[3][tid];
    __syncthreads();
  }

  // ---- phase 4: xbar[h][d] = sum_m abar[h][m] * X[m][d] (X from xbf, L2-hot)
  float a4[4][3] = {};
  for (int m = 0; m < 64; ++m) {
    float ab0 = abar_all[0][m], ab1 = abar_all[1][m];
    float ab2 = abar_all[2][m], ab3 = abar_all[3][m];
#pragma unroll
    for (int u = 0; u < 3; ++u) {
      float x = b2f(xg[(size_t)m * 768 + u * 256 + tid]);
      a4[0][u] += ab0 * x;
      a4[1][u] += ab1 * x;
      a4[2][u] += ab2 * x;
      a4[3][u] += ab3 * x;
    }
  }
  // head-major xbar: [4][1024][768]
#pragma unroll
  for (int hh = 0; hh < 4; ++hh)
#pragma unroll
    for (int u = 0; u < 3; ++u)
      xbar[((size_t)hh * 1024 + n) * 768 + u * 256 + tid] = a4[hh][u];
}

// ---------------- bf16 MFMA GEMM, 128x64 tile, grid.z-batched ----------------
// C[m, za*colz + nb + c] = sum_k A[za*Az + m*K + k] * B[za*Bz + (nb+c)*K + k]
//                          + bias[za*colz + nb + c] * sfac(cnt[m])
// Requires M%128==0 (grid.y = M/128), N per z a multiple of 64, K%32==0.
__global__ __launch_bounds__(256) void gemm_bf16_64(
    const unsigned short* __restrict__ A, const unsigned short* __restrict__ B,
    const float* __restrict__ bias, const float* __restrict__ cnt,
    float* __restrict__ C, int K, int ldc, size_t Az, size_t Bz, int colz) {
  __shared__ unsigned short smA[128 * 32];
  __shared__ unsigned short smB[64 * 32];
  const int tid = threadIdx.x;
  const int wid = tid >> 6;
  const int lane = tid & 63;
  const int za = blockIdx.z;
  A += (size_t)za * Az;
  B += (size_t)za * Bz;
  const int m0 = blockIdx.y * 128;
  const int nb = blockIdx.x * 64;
  const int wr = wid >> 1, wc = wid & 1;
  const int srow = lane >> 2;
  const int scol = (lane & 3) * 8;
  const int fr = lane & 15;
  const int fk = (lane >> 4) * 8;
  f32x4 acc[4][2] = {};
  for (int k0 = 0; k0 < K; k0 += 32) {
#pragma unroll
    for (int t = 0; t < 2; ++t) {
      const int r0 = wid * 32 + t * 16;
      gload_lds16(A + (size_t)(m0 + r0 + srow) * K + k0 + scol, &smA[r0 * 32]);
    }
    gload_lds16(B + (size_t)(nb + wid * 16 + srow) * K + k0 + scol, &smB[wid * 16 * 32]);
    __syncthreads();
    short8 af[4], bfr[2];
#pragma unroll
    for (int i = 0; i < 4; ++i)
      af[i] = *(const short8*)&smA[(wr * 64 + i * 16 + fr) * 32 + fk];
#pragma unroll
    for (int j = 0; j < 2; ++j)
      bfr[j] = *(const short8*)&smB[(wc * 32 + j * 16 + fr) * 32 + fk];
#pragma unroll
    for (int i = 0; i < 4; ++i)
#pragma unroll
      for (int j = 0; j < 2; ++j)
        acc[i][j] = __builtin_amdgcn_mfma_f32_16x16x32_bf16(af[i], bfr[j], acc[i][j], 0, 0, 0);
    __syncthreads();
  }
  const int cl = lane & 15;
  const int rg = (lane >> 4) * 4;
#pragma unroll
  for (int i = 0; i < 4; ++i) {
    const int mrow0 = m0 + wr * 64 + i * 16 + rg;
#pragma unroll
    for (int j = 0; j < 2; ++j) {
      const int gc = za * colz + nb + wc * 32 + j * 16 + cl;
      const float bv = bias[gc];
#pragma unroll
      for (int r = 0; r < 4; ++r) {
        const int m = mrow0 + r;
        float sf = 1.f;
        if (cnt) { float c = cnt[m]; sf = c / (c + 1e-10f); }
        C[(size_t)m * ldc + gc] = acc[i][j][r] + bv * sf;
      }
    }
  }
}

// ---------------- fp32 GEMM: out[m,n] = sum_k X[m*lda+k]*W[n,k] + bias[n]*sfac(m) ------
#define BM 64
#define BN 64
#define BK 16
__global__ __launch_bounds__(256) void gemm_nt(
    const float* __restrict__ X, const float* __restrict__ W,
    const float* __restrict__ bias, const float* __restrict__ cnt,
    float* __restrict__ out, int M, int N, int K, int lda, int ldc) {
  __shared__ float As[BK][BM + 4];
  __shared__ float Bs[BK][BN + 4];
  const int tid = threadIdx.x;
  const int m0 = blockIdx.y * BM;
  const int n0 = blockIdx.x * BN;
  const int tx = tid & 15, ty = tid >> 4;
  const int lr = tid >> 2;
  const int lc = (tid & 3) * 4;
  float acc[4][4];
#pragma unroll
  for (int i = 0; i < 4; ++i)
#pragma unroll
    for (int j = 0; j < 4; ++j) acc[i][j] = 0.f;
  for (int k0 = 0; k0 < K; k0 += BK) {
    float4 xa = make_float4(0.f, 0.f, 0.f, 0.f);
    if (m0 + lr < M) xa = *(const float4*)(X + (size_t)(m0 + lr) * lda + k0 + lc);
    float4 wb = *(const float4*)(W + (size_t)(n0 + lr) * K + k0 + lc);
    As[lc + 0][lr] = xa.x; As[lc + 1][lr] = xa.y; As[lc + 2][lr] = xa.z; As[lc + 3][lr] = xa.w;
    Bs[lc + 0][lr] = wb.x; Bs[lc + 1][lr] = wb.y; Bs[lc + 2][lr] = wb.z; Bs[lc + 3][lr] = wb.w;
    __syncthreads();
#pragma unroll
    for (int kk = 0; kk < BK; ++kk) {
      float4 av = *(const float4*)&As[kk][ty * 4];
      float4 bv = *(const float4*)&Bs[kk][tx * 4];
      float a4[4] = {av.x, av.y, av.z, av.w};
      float b4[4] = {bv.x, bv.y, bv.z, bv.w};
#pragma unroll
      for (int i = 0; i < 4; ++i)
#pragma unroll
        for (int j = 0; j < 4; ++j) acc[i][j] += a4[i] * b4[j];
    }
    __syncthreads();
  }
#pragma unroll
  for (int i = 0; i < 4; ++i) {
    int m = m0 + ty * 4 + i;
    if (m < M) {
      float sf = 1.f;
      if (cnt) { float c = cnt[m]; sf = c / (c + 1e-10f); }
      float4 o;
      o.x = acc[i][0] + bias[n0 + tx * 4 + 0] * sf;
      o.y = acc[i][1] + bias[n0 + tx * 4 + 1] * sf;
      o.z = acc[i][2] + bias[n0 + tx * 4 + 2] * sf;
      o.w = acc[i][3] + bias[n0 + tx * 4 + 3] * sf;
      *(float4*)(out + (size_t)m * ldc + n0 + tx * 4) = o;
    }
  }
}

// ---------------- small attention (L=16 or 8), pooled output ----------------
__global__ __launch_bounds__(256) void small_attn(
    const float* __restrict__ qkv, const float* __restrict__ maskv,
    const float* __restrict__ cnt, float* __restrict__ obar, int L) {
  const int n = blockIdx.x;
  const int h = blockIdx.y;
  const int tid = threadIdx.x;
  __shared__ float red[16][17];
  __shared__ float abar[16];
  const float* qb = qkv + (size_t)n * L * E3 + h * 192;
  const float* kb = qb + EDIM;
  const float* vb = qb + 2 * EDIM;
  const float scale = 0.07216878364870323f;
  if (tid < L * L) {
    int l = tid / L, m = tid % L;
    float s = 0.f;
    for (int dd = 0; dd < 192; ++dd) s += qb[(size_t)l * E3 + dd] * kb[(size_t)m * E3 + dd];
    s = (maskv[n * L + m] > 0.f) ? s * scale : -1e9f;
    float mx = s;
    for (int off = L >> 1; off > 0; off >>= 1) mx = fmaxf(mx, __shfl_xor(mx, off));
    float p = expf(s - mx);
    float sum = p;
    for (int off = L >> 1; off > 0; off >>= 1) sum += __shfl_xor(sum, off);
    float dn = cnt[n] + 1e-10f;
    float wl = (maskv[n * L + l] > 0.f) ? (1.f / dn) : 0.f;
    red[l][m] = p / sum * wl;
  }
  __syncthreads();
  if (tid < L) {
    float s = 0.f;
    for (int l2 = 0; l2 < L; ++l2) s += red[l2][tid];
    abar[tid] = s;
  }
  __syncthreads();
  if (tid < 192) {
    float acc = 0.f;
    for (int m = 0; m < L; ++m) acc += abar[m] * vb[(size_t)m * E3 + tid];
    obar[(size_t)n * EDIM + h * 192 + tid] = acc;
  }
}

// ---------------- fusion head: [8,768] doc -> [8,3] ----------------
__global__ __launch_bounds__(256) void head_kernel(
    const float* __restrict__ doc, const float* __restrict__ hand,
    const float* __restrict__ bp_w, const float* __restrict__ bp_b,
    const float* __restrict__ hp_w, const float* __restrict__ hp_b,
    const float* __restrict__ gate_w, const float* __restrict__ gate_b,
    const float* __restrict__ fg, const float* __restrict__ fbv,
    const float* __restrict__ fc1_w, const float* __restrict__ fc1_b,
    const float* __restrict__ g1, const float* __restrict__ b1,
    const float* __restrict__ fc2_w, const float* __restrict__ fc2_b,
    float* __restrict__ out) {
  int b = blockIdx.x, tid = threadIdx.x;
  __shared__ float bp[256], hp[256], fz[256], hz[128];
  const float* dr = doc + (size_t)b * 768;
  float acc = bp_b[tid];
  for (int k = 0; k < 768; ++k) acc += dr[k] * bp_w[(size_t)tid * 768 + k];
  bp[tid] = acc;
  const float* hr = hand + b * 20;
  float acc2 = hp_b[tid];
  for (int k = 0; k < 20; ++k) acc2 += hr[k] * hp_w[tid * 20 + k];
  hp[tid] = acc2;
  __syncthreads();
  float g = gate_b[tid];
  for (int k = 0; k < 256; ++k) g += bp[k] * gate_w[tid * 512 + k];
  for (int k = 0; k < 256; ++k) g += hp[k] * gate_w[tid * 512 + 256 + k];
  g = 1.f / (1.f + expf(-g));
  float fu = g * bp[tid] + (1.f - g) * hp[tid];
  fz[tid] = fu;
  __syncthreads();
  float mu = 0.f;
  for (int k = 0; k < 256; ++k) mu += fz[k];
  mu /= 256.f;
  float va = 0.f;
  for (int k = 0; k < 256; ++k) { float d = fz[k] - mu; va += d * d; }
  va /= 256.f;
  float fl = (fu - mu) / sqrtf(va + 1e-5f) * fg[tid] + fbv[tid];
  __syncthreads();
  fz[tid] = fl;
  __syncthreads();
  if (tid < 128) {
    float a = fc1_b[tid];
    for (int k = 0; k < 256; ++k) a += fz[k] * fc1_w[tid * 256 + k];
    hz[tid] = fmaxf(a, 0.f);
  }
  __syncthreads();
  float mu2 = 0.f;
  for (int k = 0; k < 128; ++k) mu2 += hz[k];
  mu2 /= 128.f;
  float va2 = 0.f;
  for (int k = 0; k < 128; ++k) { float d = hz[k] - mu2; va2 += d * d; }
  va2 /= 128.f;
  __syncthreads();
  if (tid < 128) hz[tid] = (hz[tid] - mu2) / sqrtf(va2 + 1e-5f) * g1[tid] + b1[tid];
  __syncthreads();
  if (tid < 3) {
    float o = fc2_b[tid];
    for (int k = 0; k < 128; ++k) o += hz[k] * fc2_w[tid * 128 + k];
    out[b * 3 + tid] = o;
  }
}

extern "C" void kernel_launch(void* const* d_in, const int* in_sizes, int n_in,
                              void* d_out, int out_size, void* d_ws, size_t ws_size,
                              hipStream_t stream) {
  const float* we      = (const float*)d_in[0];
  const int*   am      = (const int*)d_in[1];
  const float* hand    = (const float*)d_in[2];
  const float* w_w_in  = (const float*)d_in[3];
  const float* w_b_in  = (const float*)d_in[4];
  const float* w_w_out = (const float*)d_in[5];
  const float* w_b_out = (const float*)d_in[6];
  const float* s_w_in  = (const float*)d_in[7];
  const float* s_b_in  = (const float*)d_in[8];
  const float* s_w_out = (const float*)d_in[9];
  const float* s_b_out = (const float*)d_in[10];
  const float* c_w_in  = (const float*)d_in[11];
  const float* c_b_in  = (const float*)d_in[12];
  const float* c_w_out = (const float*)d_in[13];
  const float* c_b_out = (const float*)d_in[14];
  const float* bp_w = (const float*)d_in[15];
  const float* bp_b = (const float*)d_in[16];
  const float* hp_w = (const float*)d_in[17];
  const float* hp_b = (const float*)d_in[18];
  // d_in[19..22] = fa_* (cross-attention) — output unused by the reference, skipped.
  const float* gate_w = (const float*)d_in[23];
  const float* gate_b = (const float*)d_in[24];
  const float* fus_g  = (const float*)d_in[25];
  const float* fus_b  = (const float*)d_in[26];
  const float* fc1_w  = (const float*)d_in[27];
  const float* fc1_b  = (const float*)d_in[28];
  const float* ln1_g  = (const float*)d_in[29];
  const float* ln1_b  = (const float*)d_in[30];
  const float* fc2_w  = (const float*)d_in[31];
  const float* fc2_b  = (const float*)d_in[32];
  float* out = (float*)d_out;

  // carve buffers from the top of the workspace
  char* end = (char*)d_ws + ws_size;
  auto carveb = [&](size_t bytes) {
    size_t b = (bytes + 255) & ~(size_t)255;
    end -= b;
    return (void*)end;
  };
  float* xbar            = (float*)carveb((size_t)4 * 1024 * 768 * 4);   // head-major
  unsigned short* xbarbf = (unsigned short*)carveb((size_t)4 * 1024 * 768 * 2);
  float* obar1           = (float*)carveb((size_t)1024 * 768 * 4);
  unsigned short* obarbf = (unsigned short*)carveb((size_t)1024 * 768 * 2);
  float* sent            = (float*)carveb((size_t)1024 * 768 * 4);
  unsigned short* sentbf = (unsigned short*)carveb((size_t)1024 * 768 * 2);
  float* qkv2            = (float*)carveb((size_t)1024 * 2304 * 4);
  float* obar2  = (float*)carveb(64 * 768 * 4);
  float* sec    = (float*)carveb(64 * 768 * 4);
  float* qkv3   = (float*)carveb(64 * 2304 * 4);
  float* obar3  = (float*)carveb(8 * 768 * 4);
  float* doc    = (float*)carveb(8 * 768 * 4);
  float* wsum   = (float*)carveb(1024 * 4);
  float* svalid = (float*)carveb(1024 * 4);
  float* cnt2   = (float*)carveb(64 * 4);
  float* secv   = (float*)carveb(64 * 4);
  float* cnt3   = (float*)carveb(8 * 4);
  unsigned short* wbf_in = (unsigned short*)carveb((size_t)2304 * 768 * 2);
  unsigned short* wobf   = (unsigned short*)carveb((size_t)768 * 768 * 2);
  unsigned short* wsbf   = (unsigned short*)carveb((size_t)2304 * 768 * 2);

  unsigned short* xbf = (unsigned short*)d_ws;  // chunked X bf16
  size_t avail = (size_t)(end - (char*)d_ws);
  int cs = 1024;
  while (cs > 16 && (size_t)cs * 64 * 768 * 2 > avail) cs >>= 1;

  auto cgrid = [](size_t n) { size_t g = (n + 2047) / 2048; return (int)(g > 1024 ? 1024 : g); };

  // prep: weights -> bf16, mask stats
  f2bf<<<cgrid((size_t)2304 * 768), 256, 0, stream>>>(w_w_in, wbf_in, (size_t)2304 * 768);
  f2bf<<<cgrid((size_t)768 * 768), 256, 0, stream>>>(w_w_out, wobf, (size_t)768 * 768);
  f2bf<<<cgrid((size_t)2304 * 768), 256, 0, stream>>>(s_w_in, wsbf, (size_t)2304 * 768);
  mask_stats1<<<4, 256, 0, stream>>>(am, wsum, svalid);
  mask_stats2<<<1, 64, 0, stream>>>(wsum, svalid, cnt2, secv, cnt3);

  // word level: X -> bf16 (chunked), fused QK-attention -> pooled xbar [4][1024][768]
  for (int s0 = 0; s0 < 1024; s0 += cs) {
    int c = (1024 - s0 < cs) ? (1024 - s0) : cs;
    size_t nel = (size_t)c * 64 * 768;
    f2bf<<<cgrid(nel), 256, 0, stream>>>(we + (size_t)s0 * 64 * 768, xbf, nel);
    fused_word<<<c, 256, 0, stream>>>(xbf, am, wbf_in, w_b_in, wsum, xbar, s0);
  }
  // V-projection (batched per head): obar1[n, h*192+c] = xbar[h][n,:] @ Wv_h^T + bv*sfac
  f2bf<<<1024, 256, 0, stream>>>(xbar, xbarbf, (size_t)4 * 1024 * 768);
  gemm_bf16_64<<<dim3(3, 8, 4), 256, 0, stream>>>(
      xbarbf, wbf_in + (size_t)1536 * 768, w_b_in + 1536, wsum, obar1,
      768, 768, (size_t)1024 * 768, (size_t)192 * 768, 192);
  // sent = obar1 @ w_out^T + b_out * sfac
  f2bf<<<cgrid((size_t)1024 * 768), 256, 0, stream>>>(obar1, obarbf, (size_t)1024 * 768);
  gemm_bf16_64<<<dim3(12, 8, 1), 256, 0, stream>>>(
      obarbf, wobf, w_b_out, wsum, sent, 768, 768, 0, 0, 0);
  // sentence level QKV
  f2bf<<<cgrid((size_t)1024 * 768), 256, 0, stream>>>(sent, sentbf, (size_t)1024 * 768);
  gemm_bf16_64<<<dim3(36, 8, 1), 256, 0, stream>>>(
      sentbf, wsbf, s_b_in, nullptr, qkv2, 768, 2304, 0, 0, 0);
  small_attn<<<dim3(64, 4), 256, 0, stream>>>(qkv2, svalid, cnt2, obar2, 16);
  gemm_nt<<<dim3(12, 1), 256, 0, stream>>>(obar2, s_w_out, s_b_out, cnt2, sec,
                                           64, 768, 768, 768, 768);
  // section level
  gemm_nt<<<dim3(36, 1), 256, 0, stream>>>(sec, c_w_in, c_b_in, nullptr, qkv3,
                                           64, 2304, 768, 768, 2304);
  small_attn<<<dim3(8, 4), 256, 0, stream>>>(qkv3, secv, cnt3, obar3, 8);
  gemm_nt<<<dim3(12, 1), 256, 0, stream>>>(obar3, c_w_out, c_b_out, cnt3, doc,
                                           8, 768, 768, 768, 768);
  // fusion head
  head_kernel<<<8, 256, 0, stream>>>(doc, hand, bp_w, bp_b, hp_w, hp_b, gate_w, gate_b,
                                     fus_g, fus_b, fc1_w, fc1_b, ln1_g, ln1_b, fc2_w, fc2_b, out);
}

// Round 5
// 650.524 us; speedup vs baseline: 5.7118x; 1.2581x over previous
//
#include <hip/hip_runtime.h>
#include <math.h>

#define EDIM 768
#define E3 2304

typedef __attribute__((ext_vector_type(8))) short short8;
typedef __attribute__((ext_vector_type(8))) unsigned short ushort8;
typedef __attribute__((ext_vector_type(4))) float f32x4;

__device__ inline void gload_lds16(const void* g, void* l) {
  __builtin_amdgcn_global_load_lds((const __attribute__((address_space(1))) void*)g,
                                   (__attribute__((address_space(3))) void*)l, 16, 0, 0);
}

__device__ inline unsigned short f2b_rne(float f) {
  unsigned int u = __builtin_bit_cast(unsigned int, f);
  u = (u + 0x7fffu + ((u >> 16) & 1u)) >> 16;
  return (unsigned short)u;
}
__device__ inline float b2f(unsigned short u) {
  unsigned int x = ((unsigned int)u) << 16;
  return __builtin_bit_cast(float, x);
}
__device__ inline float ldv(float v) { return v; }
__device__ inline float ldv(unsigned short v) { return b2f(v); }

// ---------------- fp32 -> bf16 conversion ----------------
__global__ __launch_bounds__(256) void f2bf(const float* __restrict__ in,
                                            unsigned short* __restrict__ out, size_t n) {
  size_t i = ((size_t)blockIdx.x * blockDim.x + threadIdx.x) * 8;
  size_t stride = (size_t)gridDim.x * blockDim.x * 8;
  for (; i < n; i += stride) {
    float4 a = *(const float4*)(in + i);
    float4 b = *(const float4*)(in + i + 4);
    ushort8 o;
    o[0] = f2b_rne(a.x); o[1] = f2b_rne(a.y); o[2] = f2b_rne(a.z); o[3] = f2b_rne(a.w);
    o[4] = f2b_rne(b.x); o[5] = f2b_rne(b.y); o[6] = f2b_rne(b.z); o[7] = f2b_rne(b.w);
    *(ushort8*)(out + i) = o;
  }
}

// ---------------- mask statistics ----------------
__global__ void mask_stats1(const int* __restrict__ am, float* __restrict__ wsum,
                            float* __restrict__ svalid) {
  int n = blockIdx.x * blockDim.x + threadIdx.x;
  if (n < 1024) {
    int s = 0;
    const int* p = am + (size_t)n * 64;
    for (int w = 0; w < 64; ++w) s += p[w];
    wsum[n] = (float)s;
    svalid[n] = s > 0 ? 1.f : 0.f;
  }
}

__global__ void mask_stats2(const float* __restrict__ wsum, const float* __restrict__ svalid,
                            float* __restrict__ cnt2, float* __restrict__ secv,
                            float* __restrict__ cnt3) {
  int tid = threadIdx.x;  // 64 threads
  if (tid < 64) {
    float c = 0.f, t = 0.f;
    for (int u = 0; u < 16; ++u) { c += svalid[tid * 16 + u]; t += wsum[tid * 16 + u]; }
    cnt2[tid] = c;
    secv[tid] = t > 0.f ? 1.f : 0.f;
  }
  __syncthreads();
  if (tid < 8) {
    float c = 0.f;
    for (int s = 0; s < 8; ++s) c += secv[tid * 8 + s];
    cnt3[tid] = c;
  }
}

// ---------------- Q,K projection: bf16 MFMA GEMM, 128x128 tile, bf16 out --------
// C[m,n] = bf16( sum_k A[m,k]*B[n,k] + bias[n] ), N=1536 (Q rows 0..767, K 768..1535).
// 1D grid with bijective XCD swizzle (nwg % 8 == 0): consecutive swizzled ids share
// the A row-panel within one XCD's L2.
__global__ __launch_bounds__(256) void gemm_qk(
    const unsigned short* __restrict__ A, const unsigned short* __restrict__ B,
    const float* __restrict__ bias, unsigned short* __restrict__ C,
    int M, int N, int K) {
  __shared__ unsigned short smA[128 * 32];
  __shared__ unsigned short smB[128 * 32];
  const int tid = threadIdx.x;
  const int wid = tid >> 6;
  const int lane = tid & 63;
  const int nwg = gridDim.x;
  const int cpx = nwg >> 3;
  const int bid = blockIdx.x;
  const int swz = (bid & 7) * cpx + (bid >> 3);
  const int nbx = N / 128;
  const int m0 = (swz / nbx) * 128;
  const int n0 = (swz % nbx) * 128;
  const int wr = wid >> 1, wc = wid & 1;
  f32x4 acc[4][4] = {};
  const int srow = lane >> 2;
  const int scol = (lane & 3) * 8;
  const int fr = lane & 15;
  const int fk = (lane >> 4) * 8;
  for (int k0 = 0; k0 < K; k0 += 32) {
#pragma unroll
    for (int t = 0; t < 2; ++t) {
      const int r0 = wid * 32 + t * 16;
      gload_lds16(A + (size_t)(m0 + r0 + srow) * K + k0 + scol, &smA[r0 * 32]);
      gload_lds16(B + (size_t)(n0 + r0 + srow) * K + k0 + scol, &smB[r0 * 32]);
    }
    __syncthreads();
    short8 af[4], bf[4];
#pragma unroll
    for (int i = 0; i < 4; ++i) {
      af[i] = *(const short8*)&smA[(wr * 64 + i * 16 + fr) * 32 + fk];
      bf[i] = *(const short8*)&smB[(wc * 64 + i * 16 + fr) * 32 + fk];
    }
#pragma unroll
    for (int i = 0; i < 4; ++i)
#pragma unroll
      for (int j = 0; j < 4; ++j)
        acc[i][j] = __builtin_amdgcn_mfma_f32_16x16x32_bf16(af[i], bf[j], acc[i][j], 0, 0, 0);
    __syncthreads();
  }
  const int cl = lane & 15;
  const int rg = (lane >> 4) * 4;
#pragma unroll
  for (int i = 0; i < 4; ++i) {
    const int mrow0 = m0 + wr * 64 + i * 16 + rg;
#pragma unroll
    for (int j = 0; j < 4; ++j) {
      const int col = n0 + wc * 64 + j * 16 + cl;
      const float bv = bias[col];
#pragma unroll
      for (int r = 0; r < 4; ++r)
        C[(size_t)(mrow0 + r) * N + col] = f2b_rne(acc[i][j][r] + bv);
    }
  }
}

// ---------------- word-level attention from materialized Q,K (bf16) ----------------
// 1 block per sentence, wave = head. S = Q K^T via MFMA frags straight from global;
// in-register masked softmax + pooling weights -> abar; pooled xbar (bf16 out).
__global__ __launch_bounds__(256) void attn_qk(
    const unsigned short* __restrict__ qk, const unsigned short* __restrict__ xbf,
    const int* __restrict__ am, const float* __restrict__ wsum,
    unsigned short* __restrict__ xbarbf) {
  __shared__ float abar_all[4][64];
  __shared__ float msk[64];
  const int n = blockIdx.x;
  const int tid = threadIdx.x;
  const int h = tid >> 6;  // wave = head
  const int lane = tid & 63;
  if (tid < 64) msk[tid] = (am[(size_t)n * 64 + tid] > 0) ? 1.f : 0.f;
  __syncthreads();
  const int fr = lane & 15;
  const int fk = (lane >> 4) * 8;
  const unsigned short* Qg = qk + (size_t)n * 64 * 1536 + h * 192;
  const unsigned short* Kg = Qg + 768;
  f32x4 acc[4][4] = {};
#pragma unroll
  for (int ks = 0; ks < 6; ++ks) {
    short8 aq[4], bk[4];
#pragma unroll
    for (int i = 0; i < 4; ++i)
      aq[i] = *(const short8*)(Qg + (size_t)(i * 16 + fr) * 1536 + ks * 32 + fk);
#pragma unroll
    for (int j = 0; j < 4; ++j)
      bk[j] = *(const short8*)(Kg + (size_t)(j * 16 + fr) * 1536 + ks * 32 + fk);
#pragma unroll
    for (int i = 0; i < 4; ++i)
#pragma unroll
      for (int j = 0; j < 4; ++j)
        acc[i][j] = __builtin_amdgcn_mfma_f32_16x16x32_bf16(aq[i], bk[j], acc[i][j], 0, 0, 0);
  }
  // softmax over cols (row = i*16 + (lane>>4)*4 + r, col = j*16 + fr)
  const float den = wsum[n] + 1e-10f;
  const float scale = 0.07216878364870323f;  // 1/sqrt(192)
  float mcol[4];
#pragma unroll
  for (int j = 0; j < 4; ++j) mcol[j] = msk[j * 16 + fr];
  float colsum[4] = {0.f, 0.f, 0.f, 0.f};
#pragma unroll
  for (int i = 0; i < 4; ++i) {
#pragma unroll
    for (int r = 0; r < 4; ++r) {
      float s[4];
      float mx = -1e30f;
#pragma unroll
      for (int j = 0; j < 4; ++j) {
        float v = mcol[j] > 0.f ? acc[i][j][r] * scale : -1e9f;
        s[j] = v;
        mx = fmaxf(mx, v);
      }
      mx = fmaxf(mx, __shfl_xor(mx, 1));
      mx = fmaxf(mx, __shfl_xor(mx, 2));
      mx = fmaxf(mx, __shfl_xor(mx, 4));
      mx = fmaxf(mx, __shfl_xor(mx, 8));
      float sum = 0.f;
#pragma unroll
      for (int j = 0; j < 4; ++j) { s[j] = expf(s[j] - mx); sum += s[j]; }
      sum += __shfl_xor(sum, 1);
      sum += __shfl_xor(sum, 2);
      sum += __shfl_xor(sum, 4);
      sum += __shfl_xor(sum, 8);
      float wrow = msk[i * 16 + (lane >> 4) * 4 + r] / den;
      float f = wrow / sum;
#pragma unroll
      for (int j = 0; j < 4; ++j) colsum[j] += s[j] * f;
    }
  }
#pragma unroll
  for (int j = 0; j < 4; ++j) {
    float cs = colsum[j];
    cs += __shfl_xor(cs, 16);
    cs += __shfl_xor(cs, 32);
    if (lane < 16) abar_all[h][j * 16 + lane] = cs;
  }
  __syncthreads();
  // pooling: xbar[h][d] = sum_m abar[h][m] * X[m][d]
  const unsigned short* xg = xbf + (size_t)n * 64 * 768;
  float a4[4][3] = {};
  for (int m = 0; m < 64; ++m) {
    float ab0 = abar_all[0][m], ab1 = abar_all[1][m];
    float ab2 = abar_all[2][m], ab3 = abar_all[3][m];
#pragma unroll
    for (int u = 0; u < 3; ++u) {
      float x = b2f(xg[(size_t)m * 768 + u * 256 + tid]);
      a4[0][u] += ab0 * x;
      a4[1][u] += ab1 * x;
      a4[2][u] += ab2 * x;
      a4[3][u] += ab3 * x;
    }
  }
#pragma unroll
  for (int hh = 0; hh < 4; ++hh)
#pragma unroll
    for (int u = 0; u < 3; ++u)
      xbarbf[((size_t)hh * 1024 + n) * 768 + u * 256 + tid] = f2b_rne(a4[hh][u]);
}

// ---------------- bf16 MFMA GEMM, 128x64 tile, grid.z-batched, fp32/bf16 out ------
__global__ __launch_bounds__(256) void gemm_bf16_64(
    const unsigned short* __restrict__ A, const unsigned short* __restrict__ B,
    const float* __restrict__ bias, const float* __restrict__ cnt,
    float* __restrict__ C, unsigned short* __restrict__ Cb,
    int K, int ldc, size_t Az, size_t Bz, int colz) {
  __shared__ unsigned short smA[128 * 32];
  __shared__ unsigned short smB[64 * 32];
  const int tid = threadIdx.x;
  const int wid = tid >> 6;
  const int lane = tid & 63;
  const int za = blockIdx.z;
  A += (size_t)za * Az;
  B += (size_t)za * Bz;
  const int m0 = blockIdx.y * 128;
  const int nb = blockIdx.x * 64;
  const int wr = wid >> 1, wc = wid & 1;
  const int srow = lane >> 2;
  const int scol = (lane & 3) * 8;
  const int fr = lane & 15;
  const int fk = (lane >> 4) * 8;
  f32x4 acc[4][2] = {};
  for (int k0 = 0; k0 < K; k0 += 32) {
#pragma unroll
    for (int t = 0; t < 2; ++t) {
      const int r0 = wid * 32 + t * 16;
      gload_lds16(A + (size_t)(m0 + r0 + srow) * K + k0 + scol, &smA[r0 * 32]);
    }
    gload_lds16(B + (size_t)(nb + wid * 16 + srow) * K + k0 + scol, &smB[wid * 16 * 32]);
    __syncthreads();
    short8 af[4], bfr[2];
#pragma unroll
    for (int i = 0; i < 4; ++i)
      af[i] = *(const short8*)&smA[(wr * 64 + i * 16 + fr) * 32 + fk];
#pragma unroll
    for (int j = 0; j < 2; ++j)
      bfr[j] = *(const short8*)&smB[(wc * 32 + j * 16 + fr) * 32 + fk];
#pragma unroll
    for (int i = 0; i < 4; ++i)
#pragma unroll
      for (int j = 0; j < 2; ++j)
        acc[i][j] = __builtin_amdgcn_mfma_f32_16x16x32_bf16(af[i], bfr[j], acc[i][j], 0, 0, 0);
    __syncthreads();
  }
  const int cl = lane & 15;
  const int rg = (lane >> 4) * 4;
#pragma unroll
  for (int i = 0; i < 4; ++i) {
    const int mrow0 = m0 + wr * 64 + i * 16 + rg;
#pragma unroll
    for (int j = 0; j < 2; ++j) {
      const int gc = za * colz + nb + wc * 32 + j * 16 + cl;
      const float bv = bias[gc];
#pragma unroll
      for (int r = 0; r < 4; ++r) {
        const int m = mrow0 + r;
        float sf = 1.f;
        if (cnt) { float c = cnt[m]; sf = c / (c + 1e-10f); }
        float v = acc[i][j][r] + bv * sf;
        if (Cb) Cb[(size_t)m * ldc + gc] = f2b_rne(v);
        else C[(size_t)m * ldc + gc] = v;
      }
    }
  }
}

// ---------------- fp32 GEMM: out[m,n] = sum_k X[m*lda+k]*W[n,k] + bias[n]*sfac(m) ------
#define BM 64
#define BN 64
#define BK 16
__global__ __launch_bounds__(256) void gemm_nt(
    const float* __restrict__ X, const float* __restrict__ W,
    const float* __restrict__ bias, const float* __restrict__ cnt,
    float* __restrict__ out, int M, int N, int K, int lda, int ldc) {
  __shared__ float As[BK][BM + 4];
  __shared__ float Bs[BK][BN + 4];
  const int tid = threadIdx.x;
  const int m0 = blockIdx.y * BM;
  const int n0 = blockIdx.x * BN;
  const int tx = tid & 15, ty = tid >> 4;
  const int lr = tid >> 2;
  const int lc = (tid & 3) * 4;
  float acc[4][4];
#pragma unroll
  for (int i = 0; i < 4; ++i)
#pragma unroll
    for (int j = 0; j < 4; ++j) acc[i][j] = 0.f;
  for (int k0 = 0; k0 < K; k0 += BK) {
    float4 xa = make_float4(0.f, 0.f, 0.f, 0.f);
    if (m0 + lr < M) xa = *(const float4*)(X + (size_t)(m0 + lr) * lda + k0 + lc);
    float4 wb = *(const float4*)(W + (size_t)(n0 + lr) * K + k0 + lc);
    As[lc + 0][lr] = xa.x; As[lc + 1][lr] = xa.y; As[lc + 2][lr] = xa.z; As[lc + 3][lr] = xa.w;
    Bs[lc + 0][lr] = wb.x; Bs[lc + 1][lr] = wb.y; Bs[lc + 2][lr] = wb.z; Bs[lc + 3][lr] = wb.w;
    __syncthreads();
#pragma unroll
    for (int kk = 0; kk < BK; ++kk) {
      float4 av = *(const float4*)&As[kk][ty * 4];
      float4 bv = *(const float4*)&Bs[kk][tx * 4];
      float a4[4] = {av.x, av.y, av.z, av.w};
      float b4[4] = {bv.x, bv.y, bv.z, bv.w};
#pragma unroll
      for (int i = 0; i < 4; ++i)
#pragma unroll
        for (int j = 0; j < 4; ++j) acc[i][j] += a4[i] * b4[j];
    }
    __syncthreads();
  }
#pragma unroll
  for (int i = 0; i < 4; ++i) {
    int m = m0 + ty * 4 + i;
    if (m < M) {
      float sf = 1.f;
      if (cnt) { float c = cnt[m]; sf = c / (c + 1e-10f); }
      float4 o;
      o.x = acc[i][0] + bias[n0 + tx * 4 + 0] * sf;
      o.y = acc[i][1] + bias[n0 + tx * 4 + 1] * sf;
      o.z = acc[i][2] + bias[n0 + tx * 4 + 2] * sf;
      o.w = acc[i][3] + bias[n0 + tx * 4 + 3] * sf;
      *(float4*)(out + (size_t)m * ldc + n0 + tx * 4) = o;
    }
  }
}

// ---------------- small attention (L=16 or 8), pooled output, fp32 or bf16 qkv ----
template <class T>
__global__ __launch_bounds__(256) void small_attn(
    const T* __restrict__ qkv, const float* __restrict__ maskv,
    const float* __restrict__ cnt, float* __restrict__ obar, int L) {
  const int n = blockIdx.x;
  const int h = blockIdx.y;
  const int tid = threadIdx.x;
  __shared__ float red[16][17];
  __shared__ float abar[16];
  const T* qb = qkv + (size_t)n * L * E3 + h * 192;
  const T* kb = qb + EDIM;
  const T* vb = qb + 2 * EDIM;
  const float scale = 0.07216878364870323f;
  if (tid < L * L) {
    int l = tid / L, m = tid % L;
    float s = 0.f;
    for (int dd = 0; dd < 192; ++dd) s += ldv(qb[(size_t)l * E3 + dd]) * ldv(kb[(size_t)m * E3 + dd]);
    s = (maskv[n * L + m] > 0.f) ? s * scale : -1e9f;
    float mx = s;
    for (int off = L >> 1; off > 0; off >>= 1) mx = fmaxf(mx, __shfl_xor(mx, off));
    float p = expf(s - mx);
    float sum = p;
    for (int off = L >> 1; off > 0; off >>= 1) sum += __shfl_xor(sum, off);
    float dn = cnt[n] + 1e-10f;
    float wl = (maskv[n * L + l] > 0.f) ? (1.f / dn) : 0.f;
    red[l][m] = p / sum * wl;
  }
  __syncthreads();
  if (tid < L) {
    float s = 0.f;
    for (int l2 = 0; l2 < L; ++l2) s += red[l2][tid];
    abar[tid] = s;
  }
  __syncthreads();
  if (tid < 192) {
    float acc = 0.f;
    for (int m = 0; m < L; ++m) acc += abar[m] * ldv(vb[(size_t)m * E3 + tid]);
    obar[(size_t)n * EDIM + h * 192 + tid] = acc;
  }
}

// ---------------- fusion head: [8,768] doc -> [8,3] ----------------
__global__ __launch_bounds__(256) void head_kernel(
    const float* __restrict__ doc, const float* __restrict__ hand,
    const float* __restrict__ bp_w, const float* __restrict__ bp_b,
    const float* __restrict__ hp_w, const float* __restrict__ hp_b,
    const float* __restrict__ gate_w, const float* __restrict__ gate_b,
    const float* __restrict__ fg, const float* __restrict__ fbv,
    const float* __restrict__ fc1_w, const float* __restrict__ fc1_b,
    const float* __restrict__ g1, const float* __restrict__ b1,
    const float* __restrict__ fc2_w, const float* __restrict__ fc2_b,
    float* __restrict__ out) {
  int b = blockIdx.x, tid = threadIdx.x;
  __shared__ float bp[256], hp[256], fz[256], hz[128];
  const float* dr = doc + (size_t)b * 768;
  float acc = bp_b[tid];
  for (int k = 0; k < 768; ++k) acc += dr[k] * bp_w[(size_t)tid * 768 + k];
  bp[tid] = acc;
  const float* hr = hand + b * 20;
  float acc2 = hp_b[tid];
  for (int k = 0; k < 20; ++k) acc2 += hr[k] * hp_w[tid * 20 + k];
  hp[tid] = acc2;
  __syncthreads();
  float g = gate_b[tid];
  for (int k = 0; k < 256; ++k) g += bp[k] * gate_w[tid * 512 + k];
  for (int k = 0; k < 256; ++k) g += hp[k] * gate_w[tid * 512 + 256 + k];
  g = 1.f / (1.f + expf(-g));
  float fu = g * bp[tid] + (1.f - g) * hp[tid];
  fz[tid] = fu;
  __syncthreads();
  float mu = 0.f;
  for (int k = 0; k < 256; ++k) mu += fz[k];
  mu /= 256.f;
  float va = 0.f;
  for (int k = 0; k < 256; ++k) { float d = fz[k] - mu; va += d * d; }
  va /= 256.f;
  float fl = (fu - mu) / sqrtf(va + 1e-5f) * fg[tid] + fbv[tid];
  __syncthreads();
  fz[tid] = fl;
  __syncthreads();
  if (tid < 128) {
    float a = fc1_b[tid];
    for (int k = 0; k < 256; ++k) a += fz[k] * fc1_w[tid * 256 + k];
    hz[tid] = fmaxf(a, 0.f);
  }
  __syncthreads();
  float mu2 = 0.f;
  for (int k = 0; k < 128; ++k) mu2 += hz[k];
  mu2 /= 128.f;
  float va2 = 0.f;
  for (int k = 0; k < 128; ++k) { float d = hz[k] - mu2; va2 += d * d; }
  va2 /= 128.f;
  __syncthreads();
  if (tid < 128) hz[tid] = (hz[tid] - mu2) / sqrtf(va2 + 1e-5f) * g1[tid] + b1[tid];
  __syncthreads();
  if (tid < 3) {
    float o = fc2_b[tid];
    for (int k = 0; k < 128; ++k) o += hz[k] * fc2_w[tid * 128 + k];
    out[b * 3 + tid] = o;
  }
}

extern "C" void kernel_launch(void* const* d_in, const int* in_sizes, int n_in,
                              void* d_out, int out_size, void* d_ws, size_t ws_size,
                              hipStream_t stream) {
  const float* we      = (const float*)d_in[0];
  const int*   am      = (const int*)d_in[1];
  const float* hand    = (const float*)d_in[2];
  const float* w_w_in  = (const float*)d_in[3];
  const float* w_b_in  = (const float*)d_in[4];
  const float* w_w_out = (const float*)d_in[5];
  const float* w_b_out = (const float*)d_in[6];
  const float* s_w_in  = (const float*)d_in[7];
  const float* s_b_in  = (const float*)d_in[8];
  const float* s_w_out = (const float*)d_in[9];
  const float* s_b_out = (const float*)d_in[10];
  const float* c_w_in  = (const float*)d_in[11];
  const float* c_b_in  = (const float*)d_in[12];
  const float* c_w_out = (const float*)d_in[13];
  const float* c_b_out = (const float*)d_in[14];
  const float* bp_w = (const float*)d_in[15];
  const float* bp_b = (const float*)d_in[16];
  const float* hp_w = (const float*)d_in[17];
  const float* hp_b = (const float*)d_in[18];
  // d_in[19..22] = fa_* (cross-attention) — output unused by the reference, skipped.
  const float* gate_w = (const float*)d_in[23];
  const float* gate_b = (const float*)d_in[24];
  const float* fus_g  = (const float*)d_in[25];
  const float* fus_b  = (const float*)d_in[26];
  const float* fc1_w  = (const float*)d_in[27];
  const float* fc1_b  = (const float*)d_in[28];
  const float* ln1_g  = (const float*)d_in[29];
  const float* ln1_b  = (const float*)d_in[30];
  const float* fc2_w  = (const float*)d_in[31];
  const float* fc2_b  = (const float*)d_in[32];
  float* out = (float*)d_out;

  // big buffers at the bottom of the workspace
  unsigned short* qk  = (unsigned short*)d_ws;                      // [65536][1536] bf16
  unsigned short* xbf = qk + (size_t)65536 * 1536;                  // [65536][768]  bf16

  // small buffers carved from the top
  char* end = (char*)d_ws + ws_size;
  auto carveb = [&](size_t bytes) {
    size_t b = (bytes + 255) & ~(size_t)255;
    end -= b;
    return (void*)end;
  };
  unsigned short* xbarbf  = (unsigned short*)carveb((size_t)4 * 1024 * 768 * 2);
  unsigned short* obarbf  = (unsigned short*)carveb((size_t)1024 * 768 * 2);
  unsigned short* sentbf  = (unsigned short*)carveb((size_t)1024 * 768 * 2);
  unsigned short* qkv2bf  = (unsigned short*)carveb((size_t)1024 * 2304 * 2);
  float* obar2  = (float*)carveb(64 * 768 * 4);
  float* sec    = (float*)carveb(64 * 768 * 4);
  float* qkv3   = (float*)carveb(64 * 2304 * 4);
  float* obar3  = (float*)carveb(8 * 768 * 4);
  float* doc    = (float*)carveb(8 * 768 * 4);
  float* wsum   = (float*)carveb(1024 * 4);
  float* svalid = (float*)carveb(1024 * 4);
  float* cnt2   = (float*)carveb(64 * 4);
  float* secv   = (float*)carveb(64 * 4);
  float* cnt3   = (float*)carveb(8 * 4);
  unsigned short* wbf_in = (unsigned short*)carveb((size_t)2304 * 768 * 2);
  unsigned short* wobf   = (unsigned short*)carveb((size_t)768 * 768 * 2);
  unsigned short* wsbf   = (unsigned short*)carveb((size_t)2304 * 768 * 2);

  auto cgrid = [](size_t n) { size_t g = (n + 2047) / 2048; return (int)(g > 2048 ? 2048 : g); };

  // prep: weights -> bf16, mask stats
  f2bf<<<cgrid((size_t)2304 * 768), 256, 0, stream>>>(w_w_in, wbf_in, (size_t)2304 * 768);
  f2bf<<<cgrid((size_t)768 * 768), 256, 0, stream>>>(w_w_out, wobf, (size_t)768 * 768);
  f2bf<<<cgrid((size_t)2304 * 768), 256, 0, stream>>>(s_w_in, wsbf, (size_t)2304 * 768);
  mask_stats1<<<4, 256, 0, stream>>>(am, wsum, svalid);
  mask_stats2<<<1, 64, 0, stream>>>(wsum, svalid, cnt2, secv, cnt3);

  // word level
  f2bf<<<2048, 256, 0, stream>>>(we, xbf, (size_t)65536 * 768);
  gemm_qk<<<512 * 12, 256, 0, stream>>>(xbf, wbf_in, w_b_in, qk, 65536, 1536, 768);
  attn_qk<<<1024, 256, 0, stream>>>(qk, xbf, am, wsum, xbarbf);
  // V-projection (batched per head): obar[n, h*192+c] = xbar[h][n,:] @ Wv_h^T + bv*sfac
  gemm_bf16_64<<<dim3(3, 8, 4), 256, 0, stream>>>(
      xbarbf, wbf_in + (size_t)1536 * 768, w_b_in + 1536, wsum, nullptr, obarbf,
      768, 768, (size_t)1024 * 768, (size_t)192 * 768, 192);
  // sent = obar @ w_out^T + b_out * sfac
  gemm_bf16_64<<<dim3(12, 8, 1), 256, 0, stream>>>(
      obarbf, wobf, w_b_out, wsum, nullptr, sentbf, 768, 768, 0, 0, 0);
  // sentence level QKV
  gemm_bf16_64<<<dim3(36, 8, 1), 256, 0, stream>>>(
      sentbf, wsbf, s_b_in, nullptr, nullptr, qkv2bf, 768, 2304, 0, 0, 0);
  small_attn<<<dim3(64, 4), 256, 0, stream>>>(qkv2bf, svalid, cnt2, obar2, 16);
  gemm_nt<<<dim3(12, 1), 256, 0, stream>>>(obar2, s_w_out, s_b_out, cnt2, sec,
                                           64, 768, 768, 768, 768);
  // section level
  gemm_nt<<<dim3(36, 1), 256, 0, stream>>>(sec, c_w_in, c_b_in, nullptr, qkv3,
                                           64, 2304, 768, 768, 2304);
  small_attn<<<dim3(8, 4), 256, 0, stream>>>(qkv3, secv, cnt3, obar3, 8);
  gemm_nt<<<dim3(12, 1), 256, 0, stream>>>(obar3, c_w_out, c_b_out, cnt3, doc,
                                           8, 768, 768, 768, 768);
  // fusion head
  head_kernel<<<8, 256, 0, stream>>>(doc, hand, bp_w, bp_b, hp_w, hp_b, gate_w, gate_b,
                                     fus_g, fus_b, fc1_w, fc1_b, ln1_g, ln1_b, fc2_w, fc2_b, out);
}

// Round 6
// 602.454 us; speedup vs baseline: 6.1675x; 1.0798x over previous
//
#include <hip/hip_runtime.h>
#include <math.h>

#define EDIM 768
#define E3 2304
#define NT8 24  // K=768 / BK=32

typedef __attribute__((ext_vector_type(8))) short short8;
typedef __attribute__((ext_vector_type(8))) unsigned short ushort8;
typedef __attribute__((ext_vector_type(4))) float f32x4;

__device__ inline void gload_lds16(const void* g, void* l) {
  __builtin_amdgcn_global_load_lds((const __attribute__((address_space(1))) void*)g,
                                   (__attribute__((address_space(3))) void*)l, 16, 0, 0);
}

__device__ inline unsigned short f2b_rne(float f) {
  unsigned int u = __builtin_bit_cast(unsigned int, f);
  u = (u + 0x7fffu + ((u >> 16) & 1u)) >> 16;
  return (unsigned short)u;
}
__device__ inline float b2f(unsigned short u) {
  unsigned int x = ((unsigned int)u) << 16;
  return __builtin_bit_cast(float, x);
}
__device__ inline float ldv(float v) { return v; }
__device__ inline float ldv(unsigned short v) { return b2f(v); }

// ---------------- fp32 -> bf16 conversion ----------------
__global__ __launch_bounds__(256) void f2bf(const float* __restrict__ in,
                                            unsigned short* __restrict__ out, size_t n) {
  size_t i = ((size_t)blockIdx.x * blockDim.x + threadIdx.x) * 8;
  size_t stride = (size_t)gridDim.x * blockDim.x * 8;
  for (; i < n; i += stride) {
    float4 a = *(const float4*)(in + i);
    float4 b = *(const float4*)(in + i + 4);
    ushort8 o;
    o[0] = f2b_rne(a.x); o[1] = f2b_rne(a.y); o[2] = f2b_rne(a.z); o[3] = f2b_rne(a.w);
    o[4] = f2b_rne(b.x); o[5] = f2b_rne(b.y); o[6] = f2b_rne(b.z); o[7] = f2b_rne(b.w);
    *(ushort8*)(out + i) = o;
  }
}

// ---------------- mask statistics ----------------
__global__ void mask_stats1(const int* __restrict__ am, float* __restrict__ wsum,
                            float* __restrict__ svalid) {
  int n = blockIdx.x * blockDim.x + threadIdx.x;
  if (n < 1024) {
    int s = 0;
    const int* p = am + (size_t)n * 64;
    for (int w = 0; w < 64; ++w) s += p[w];
    wsum[n] = (float)s;
    svalid[n] = s > 0 ? 1.f : 0.f;
  }
}

__global__ void mask_stats2(const float* __restrict__ wsum, const float* __restrict__ svalid,
                            float* __restrict__ cnt2, float* __restrict__ secv,
                            float* __restrict__ cnt3) {
  int tid = threadIdx.x;  // 64 threads
  if (tid < 64) {
    float c = 0.f, t = 0.f;
    for (int u = 0; u < 16; ++u) { c += svalid[tid * 16 + u]; t += wsum[tid * 16 + u]; }
    cnt2[tid] = c;
    secv[tid] = t > 0.f ? 1.f : 0.f;
  }
  __syncthreads();
  if (tid < 8) {
    float c = 0.f;
    for (int s = 0; s < 8; ++s) c += secv[tid * 8 + s];
    cnt3[tid] = c;
  }
}

// ---------------- Q,K projection: phase-scheduled bf16 MFMA GEMM ----------------
// 256x256 tile, BK=32, 8 waves (2Mx4N), ring of 4 LDS K-tile slots (128 KiB),
// counted vmcnt(8) (3-tile prefetch depth), raw barriers + setprio around MFMA,
// 16B-chunk XOR bank-swizzle applied on pre-swizzled global source + frag read.
// C = bf16(A @ B^T + bias). Requires M%256==0, N%256==0, K==768.
__global__ __launch_bounds__(512, 2) void gemm8(
    const unsigned short* __restrict__ A, const unsigned short* __restrict__ B,
    const float* __restrict__ bias, unsigned short* __restrict__ C,
    int M, int N, int K) {
  __shared__ unsigned short lds[4][2][8192];  // [slot][A/B][256 rows x 32 cols]
  const int tid = threadIdx.x;
  const int w = tid >> 6;
  const int lane = tid & 63;
  const int nbx = N / 256;
  const int nwg = gridDim.x;
  const int cpx = nwg >> 3;
  const int bid = blockIdx.x;
  const int swz = (bid & 7) * cpx + (bid >> 3);
  const int m0 = (swz / nbx) * 256;
  const int n0 = (swz % nbx) * 256;
  const int wr = w >> 2, wc = w & 3;  // 2x4 wave grid; per-wave C: 128x64
  const int fr = lane & 15;
  const int g = lane >> 4;  // k-chunk (8 bf16 = 16B) for frag reads
  f32x4 acc[8][4] = {};

  // staging: call q covers LDS 16B-slots S = q*512 + tid (linear lane order).
  // slot S holds source chunk (row = S>>2, gsrc = (S&3) ^ ((row>>1)&3)).
  int srow[2], scol[2];
#pragma unroll
  for (int q = 0; q < 2; ++q) {
    int S = q * 512 + tid;
    int row = S >> 2;
    srow[q] = row;
    scol[q] = ((S & 3) ^ ((row >> 1) & 3)) * 8;
  }
  auto stageA = [&](int t) {
    const int kt = t * 32;
#pragma unroll
    for (int q = 0; q < 2; ++q)
      gload_lds16(A + (size_t)(m0 + srow[q]) * K + kt + scol[q],
                  &lds[t & 3][0][(q * 8 + w) * 512]);
  };
  auto stageB = [&](int t) {
    const int kt = t * 32;
#pragma unroll
    for (int q = 0; q < 2; ++q)
      gload_lds16(B + (size_t)(n0 + srow[q]) * K + kt + scol[q],
                  &lds[t & 3][1][(q * 8 + w) * 512]);
  };
  // fragment read offsets (ushort units): chunk slot = row*4 + (g ^ ((row>>1)&3))
  int aoff[8], boff[4];
#pragma unroll
  for (int i = 0; i < 8; ++i) {
    int r = wr * 128 + i * 16 + fr;
    aoff[i] = (r * 4 + (g ^ ((r >> 1) & 3))) * 8;
  }
#pragma unroll
  for (int j = 0; j < 4; ++j) {
    int r = wc * 64 + j * 16 + fr;
    boff[j] = (r * 4 + (g ^ ((r >> 1) & 3))) * 8;
  }

  // prologue: stage tiles 0,1,2 (12 per-wave loads); wait for tile 0 (vmcnt 8)
  stageA(0); stageB(0); stageA(1); stageB(1); stageA(2); stageB(2);
  asm volatile("s_waitcnt vmcnt(8)" ::: "memory");
  __builtin_amdgcn_sched_barrier(0);
  __builtin_amdgcn_s_barrier();
  __builtin_amdgcn_sched_barrier(0);

  for (int t = 0; t < NT8; ++t) {
    const unsigned short* la = lds[t & 3][0];
    const unsigned short* lb = lds[t & 3][1];
    short8 av[8], bv0, bv1;
    // ---- phase 0: read all A-frags + B-frags 0,1; stage A of tile t+3
#pragma unroll
    for (int i = 0; i < 8; ++i) av[i] = *(const short8*)(la + aoff[i]);
    bv0 = *(const short8*)(lb + boff[0]);
    bv1 = *(const short8*)(lb + boff[1]);
    if (t + 3 < NT8) stageA(t + 3);
    __builtin_amdgcn_sched_barrier(0);
    __builtin_amdgcn_s_barrier();
    __builtin_amdgcn_sched_barrier(0);
    __builtin_amdgcn_s_setprio(1);
#pragma unroll
    for (int i = 0; i < 8; ++i) {
      acc[i][0] = __builtin_amdgcn_mfma_f32_16x16x32_bf16(av[i], bv0, acc[i][0], 0, 0, 0);
      acc[i][1] = __builtin_amdgcn_mfma_f32_16x16x32_bf16(av[i], bv1, acc[i][1], 0, 0, 0);
    }
    __builtin_amdgcn_s_setprio(0);
    __builtin_amdgcn_sched_barrier(0);
    __builtin_amdgcn_s_barrier();
    __builtin_amdgcn_sched_barrier(0);
    // ---- phase 1: read B-frags 2,3; stage B of tile t+3
    bv0 = *(const short8*)(lb + boff[2]);
    bv1 = *(const short8*)(lb + boff[3]);
    if (t + 3 < NT8) stageB(t + 3);
    __builtin_amdgcn_sched_barrier(0);
    __builtin_amdgcn_s_barrier();
    __builtin_amdgcn_sched_barrier(0);
    __builtin_amdgcn_s_setprio(1);
#pragma unroll
    for (int i = 0; i < 8; ++i) {
      acc[i][2] = __builtin_amdgcn_mfma_f32_16x16x32_bf16(av[i], bv0, acc[i][2], 0, 0, 0);
      acc[i][3] = __builtin_amdgcn_mfma_f32_16x16x32_bf16(av[i], bv1, acc[i][3], 0, 0, 0);
    }
    __builtin_amdgcn_s_setprio(0);
    // tile boundary: ensure tile t+1 landed; keep t+2,t+3 in flight (counted)
    if (t < NT8 - 3) {
      asm volatile("s_waitcnt vmcnt(8)" ::: "memory");
    } else if (t == NT8 - 3) {
      asm volatile("s_waitcnt vmcnt(4)" ::: "memory");
    } else {
      asm volatile("s_waitcnt vmcnt(0)" ::: "memory");
    }
    __builtin_amdgcn_sched_barrier(0);
    __builtin_amdgcn_s_barrier();
    __builtin_amdgcn_sched_barrier(0);
  }

  // epilogue: bias + bf16 store
  const int cl = lane & 15;
  const int rg = (lane >> 4) * 4;
#pragma unroll
  for (int i = 0; i < 8; ++i) {
    const int mrow0 = m0 + wr * 128 + i * 16 + rg;
#pragma unroll
    for (int j = 0; j < 4; ++j) {
      const int col = n0 + wc * 64 + j * 16 + cl;
      const float bvv = bias[col];
#pragma unroll
      for (int r = 0; r < 4; ++r)
        C[(size_t)(mrow0 + r) * N + col] = f2b_rne(acc[i][j][r] + bvv);
    }
  }
}

// ---------------- word-level attention from materialized Q,K (bf16) ----------------
__global__ __launch_bounds__(256) void attn_qk(
    const unsigned short* __restrict__ qk, const unsigned short* __restrict__ xbf,
    const int* __restrict__ am, const float* __restrict__ wsum,
    unsigned short* __restrict__ xbarbf) {
  __shared__ float abar_all[4][64];
  __shared__ float msk[64];
  const int n = blockIdx.x;
  const int tid = threadIdx.x;
  const int h = tid >> 6;  // wave = head
  const int lane = tid & 63;
  if (tid < 64) msk[tid] = (am[(size_t)n * 64 + tid] > 0) ? 1.f : 0.f;
  __syncthreads();
  const int fr = lane & 15;
  const int fk = (lane >> 4) * 8;
  const unsigned short* Qg = qk + (size_t)n * 64 * 1536 + h * 192;
  const unsigned short* Kg = Qg + 768;
  f32x4 acc[4][4] = {};
#pragma unroll
  for (int ks = 0; ks < 6; ++ks) {
    short8 aq[4], bk[4];
#pragma unroll
    for (int i = 0; i < 4; ++i)
      aq[i] = *(const short8*)(Qg + (size_t)(i * 16 + fr) * 1536 + ks * 32 + fk);
#pragma unroll
    for (int j = 0; j < 4; ++j)
      bk[j] = *(const short8*)(Kg + (size_t)(j * 16 + fr) * 1536 + ks * 32 + fk);
#pragma unroll
    for (int i = 0; i < 4; ++i)
#pragma unroll
      for (int j = 0; j < 4; ++j)
        acc[i][j] = __builtin_amdgcn_mfma_f32_16x16x32_bf16(aq[i], bk[j], acc[i][j], 0, 0, 0);
  }
  const float den = wsum[n] + 1e-10f;
  const float scale = 0.07216878364870323f;  // 1/sqrt(192)
  float mcol[4];
#pragma unroll
  for (int j = 0; j < 4; ++j) mcol[j] = msk[j * 16 + fr];
  float colsum[4] = {0.f, 0.f, 0.f, 0.f};
#pragma unroll
  for (int i = 0; i < 4; ++i) {
#pragma unroll
    for (int r = 0; r < 4; ++r) {
      float s[4];
      float mx = -1e30f;
#pragma unroll
      for (int j = 0; j < 4; ++j) {
        float v = mcol[j] > 0.f ? acc[i][j][r] * scale : -1e9f;
        s[j] = v;
        mx = fmaxf(mx, v);
      }
      mx = fmaxf(mx, __shfl_xor(mx, 1));
      mx = fmaxf(mx, __shfl_xor(mx, 2));
      mx = fmaxf(mx, __shfl_xor(mx, 4));
      mx = fmaxf(mx, __shfl_xor(mx, 8));
      float sum = 0.f;
#pragma unroll
      for (int j = 0; j < 4; ++j) { s[j] = expf(s[j] - mx); sum += s[j]; }
      sum += __shfl_xor(sum, 1);
      sum += __shfl_xor(sum, 2);
      sum += __shfl_xor(sum, 4);
      sum += __shfl_xor(sum, 8);
      float wrow = msk[i * 16 + (lane >> 4) * 4 + r] / den;
      float f = wrow / sum;
#pragma unroll
      for (int j = 0; j < 4; ++j) colsum[j] += s[j] * f;
    }
  }
#pragma unroll
  for (int j = 0; j < 4; ++j) {
    float cs = colsum[j];
    cs += __shfl_xor(cs, 16);
    cs += __shfl_xor(cs, 32);
    if (lane < 16) abar_all[h][j * 16 + lane] = cs;
  }
  __syncthreads();
  const unsigned short* xg = xbf + (size_t)n * 64 * 768;
  float a4[4][3] = {};
  for (int m = 0; m < 64; ++m) {
    float ab0 = abar_all[0][m], ab1 = abar_all[1][m];
    float ab2 = abar_all[2][m], ab3 = abar_all[3][m];
#pragma unroll
    for (int u = 0; u < 3; ++u) {
      float x = b2f(xg[(size_t)m * 768 + u * 256 + tid]);
      a4[0][u] += ab0 * x;
      a4[1][u] += ab1 * x;
      a4[2][u] += ab2 * x;
      a4[3][u] += ab3 * x;
    }
  }
#pragma unroll
  for (int hh = 0; hh < 4; ++hh)
#pragma unroll
    for (int u = 0; u < 3; ++u)
      xbarbf[((size_t)hh * 1024 + n) * 768 + u * 256 + tid] = f2b_rne(a4[hh][u]);
}

// ---------------- bf16 MFMA GEMM, 128x64 tile, grid.z-batched, fp32/bf16 out ------
__global__ __launch_bounds__(256) void gemm_bf16_64(
    const unsigned short* __restrict__ A, const unsigned short* __restrict__ B,
    const float* __restrict__ bias, const float* __restrict__ cnt,
    float* __restrict__ C, unsigned short* __restrict__ Cb,
    int K, int ldc, size_t Az, size_t Bz, int colz) {
  __shared__ unsigned short smA[128 * 32];
  __shared__ unsigned short smB[64 * 32];
  const int tid = threadIdx.x;
  const int wid = tid >> 6;
  const int lane = tid & 63;
  const int za = blockIdx.z;
  A += (size_t)za * Az;
  B += (size_t)za * Bz;
  const int m0 = blockIdx.y * 128;
  const int nb = blockIdx.x * 64;
  const int wr = wid >> 1, wc = wid & 1;
  const int srow = lane >> 2;
  const int scol = (lane & 3) * 8;
  const int fr = lane & 15;
  const int fk = (lane >> 4) * 8;
  f32x4 acc[4][2] = {};
  for (int k0 = 0; k0 < K; k0 += 32) {
#pragma unroll
    for (int t = 0; t < 2; ++t) {
      const int r0 = wid * 32 + t * 16;
      gload_lds16(A + (size_t)(m0 + r0 + srow) * K + k0 + scol, &smA[r0 * 32]);
    }
    gload_lds16(B + (size_t)(nb + wid * 16 + srow) * K + k0 + scol, &smB[wid * 16 * 32]);
    __syncthreads();
    short8 af[4], bfr[2];
#pragma unroll
    for (int i = 0; i < 4; ++i)
      af[i] = *(const short8*)&smA[(wr * 64 + i * 16 + fr) * 32 + fk];
#pragma unroll
    for (int j = 0; j < 2; ++j)
      bfr[j] = *(const short8*)&smB[(wc * 32 + j * 16 + fr) * 32 + fk];
#pragma unroll
    for (int i = 0; i < 4; ++i)
#pragma unroll
      for (int j = 0; j < 2; ++j)
        acc[i][j] = __builtin_amdgcn_mfma_f32_16x16x32_bf16(af[i], bfr[j], acc[i][j], 0, 0, 0);
    __syncthreads();
  }
  const int cl = lane & 15;
  const int rg = (lane >> 4) * 4;
#pragma unroll
  for (int i = 0; i < 4; ++i) {
    const int mrow0 = m0 + wr * 64 + i * 16 + rg;
#pragma unroll
    for (int j = 0; j < 2; ++j) {
      const int gc = za * colz + nb + wc * 32 + j * 16 + cl;
      const float bv = bias[gc];
#pragma unroll
      for (int r = 0; r < 4; ++r) {
        const int m = mrow0 + r;
        float sf = 1.f;
        if (cnt) { float c = cnt[m]; sf = c / (c + 1e-10f); }
        float v = acc[i][j][r] + bv * sf;
        if (Cb) Cb[(size_t)m * ldc + gc] = f2b_rne(v);
        else C[(size_t)m * ldc + gc] = v;
      }
    }
  }
}

// ---------------- fp32 GEMM: out[m,n] = sum_k X[m*lda+k]*W[n,k] + bias[n]*sfac(m) ------
#define BM 64
#define BN 64
#define BK 16
__global__ __launch_bounds__(256) void gemm_nt(
    const float* __restrict__ X, const float* __restrict__ W,
    const float* __restrict__ bias, const float* __restrict__ cnt,
    float* __restrict__ out, int M, int N, int K, int lda, int ldc) {
  __shared__ float As[BK][BM + 4];
  __shared__ float Bs[BK][BN + 4];
  const int tid = threadIdx.x;
  const int m0 = blockIdx.y * BM;
  const int n0 = blockIdx.x * BN;
  const int tx = tid & 15, ty = tid >> 4;
  const int lr = tid >> 2;
  const int lc = (tid & 3) * 4;
  float acc[4][4];
#pragma unroll
  for (int i = 0; i < 4; ++i)
#pragma unroll
    for (int j = 0; j < 4; ++j) acc[i][j] = 0.f;
  for (int k0 = 0; k0 < K; k0 += BK) {
    float4 xa = make_float4(0.f, 0.f, 0.f, 0.f);
    if (m0 + lr < M) xa = *(const float4*)(X + (size_t)(m0 + lr) * lda + k0 + lc);
    float4 wb = *(const float4*)(W + (size_t)(n0 + lr) * K + k0 + lc);
    As[lc + 0][lr] = xa.x; As[lc + 1][lr] = xa.y; As[lc + 2][lr] = xa.z; As[lc + 3][lr] = xa.w;
    Bs[lc + 0][lr] = wb.x; Bs[lc + 1][lr] = wb.y; Bs[lc + 2][lr] = wb.z; Bs[lc + 3][lr] = wb.w;
    __syncthreads();
#pragma unroll
    for (int kk = 0; kk < BK; ++kk) {
      float4 av = *(const float4*)&As[kk][ty * 4];
      float4 bv = *(const float4*)&Bs[kk][tx * 4];
      float a4[4] = {av.x, av.y, av.z, av.w};
      float b4[4] = {bv.x, bv.y, bv.z, bv.w};
#pragma unroll
      for (int i = 0; i < 4; ++i)
#pragma unroll
        for (int j = 0; j < 4; ++j) acc[i][j] += a4[i] * b4[j];
    }
    __syncthreads();
  }
#pragma unroll
  for (int i = 0; i < 4; ++i) {
    int m = m0 + ty * 4 + i;
    if (m < M) {
      float sf = 1.f;
      if (cnt) { float c = cnt[m]; sf = c / (c + 1e-10f); }
      float4 o;
      o.x = acc[i][0] + bias[n0 + tx * 4 + 0] * sf;
      o.y = acc[i][1] + bias[n0 + tx * 4 + 1] * sf;
      o.z = acc[i][2] + bias[n0 + tx * 4 + 2] * sf;
      o.w = acc[i][3] + bias[n0 + tx * 4 + 3] * sf;
      *(float4*)(out + (size_t)m * ldc + n0 + tx * 4) = o;
    }
  }
}

// ---------------- small attention (L=16 or 8), pooled output, fp32 or bf16 qkv ----
template <class T>
__global__ __launch_bounds__(256) void small_attn(
    const T* __restrict__ qkv, const float* __restrict__ maskv,
    const float* __restrict__ cnt, float* __restrict__ obar, int L) {
  const int n = blockIdx.x;
  const int h = blockIdx.y;
  const int tid = threadIdx.x;
  __shared__ float red[16][17];
  __shared__ float abar[16];
  const T* qb = qkv + (size_t)n * L * E3 + h * 192;
  const T* kb = qb + EDIM;
  const T* vb = qb + 2 * EDIM;
  const float scale = 0.07216878364870323f;
  if (tid < L * L) {
    int l = tid / L, m = tid % L;
    float s = 0.f;
    for (int dd = 0; dd < 192; ++dd) s += ldv(qb[(size_t)l * E3 + dd]) * ldv(kb[(size_t)m * E3 + dd]);
    s = (maskv[n * L + m] > 0.f) ? s * scale : -1e9f;
    float mx = s;
    for (int off = L >> 1; off > 0; off >>= 1) mx = fmaxf(mx, __shfl_xor(mx, off));
    float p = expf(s - mx);
    float sum = p;
    for (int off = L >> 1; off > 0; off >>= 1) sum += __shfl_xor(sum, off);
    float dn = cnt[n] + 1e-10f;
    float wl = (maskv[n * L + l] > 0.f) ? (1.f / dn) : 0.f;
    red[l][m] = p / sum * wl;
  }
  __syncthreads();
  if (tid < L) {
    float s = 0.f;
    for (int l2 = 0; l2 < L; ++l2) s += red[l2][tid];
    abar[tid] = s;
  }
  __syncthreads();
  if (tid < 192) {
    float acc = 0.f;
    for (int m = 0; m < L; ++m) acc += abar[m] * ldv(vb[(size_t)m * E3 + tid]);
    obar[(size_t)n * EDIM + h * 192 + tid] = acc;
  }
}

// ---------------- fusion head: [8,768] doc -> [8,3] ----------------
__global__ __launch_bounds__(256) void head_kernel(
    const float* __restrict__ doc, const float* __restrict__ hand,
    const float* __restrict__ bp_w, const float* __restrict__ bp_b,
    const float* __restrict__ hp_w, const float* __restrict__ hp_b,
    const float* __restrict__ gate_w, const float* __restrict__ gate_b,
    const float* __restrict__ fg, const float* __restrict__ fbv,
    const float* __restrict__ fc1_w, const float* __restrict__ fc1_b,
    const float* __restrict__ g1, const float* __restrict__ b1,
    const float* __restrict__ fc2_w, const float* __restrict__ fc2_b,
    float* __restrict__ out) {
  int b = blockIdx.x, tid = threadIdx.x;
  __shared__ float bp[256], hp[256], fz[256], hz[128];
  const float* dr = doc + (size_t)b * 768;
  float acc = bp_b[tid];
  for (int k = 0; k < 768; ++k) acc += dr[k] * bp_w[(size_t)tid * 768 + k];
  bp[tid] = acc;
  const float* hr = hand + b * 20;
  float acc2 = hp_b[tid];
  for (int k = 0; k < 20; ++k) acc2 += hr[k] * hp_w[tid * 20 + k];
  hp[tid] = acc2;
  __syncthreads();
  float g = gate_b[tid];
  for (int k = 0; k < 256; ++k) g += bp[k] * gate_w[tid * 512 + k];
  for (int k = 0; k < 256; ++k) g += hp[k] * gate_w[tid * 512 + 256 + k];
  g = 1.f / (1.f + expf(-g));
  float fu = g * bp[tid] + (1.f - g) * hp[tid];
  fz[tid] = fu;
  __syncthreads();
  float mu = 0.f;
  for (int k = 0; k < 256; ++k) mu += fz[k];
  mu /= 256.f;
  float va = 0.f;
  for (int k = 0; k < 256; ++k) { float d = fz[k] - mu; va += d * d; }
  va /= 256.f;
  float fl = (fu - mu) / sqrtf(va + 1e-5f) * fg[tid] + fbv[tid];
  __syncthreads();
  fz[tid] = fl;
  __syncthreads();
  if (tid < 128) {
    float a = fc1_b[tid];
    for (int k = 0; k < 256; ++k) a += fz[k] * fc1_w[tid * 256 + k];
    hz[tid] = fmaxf(a, 0.f);
  }
  __syncthreads();
  float mu2 = 0.f;
  for (int k = 0; k < 128; ++k) mu2 += hz[k];
  mu2 /= 128.f;
  float va2 = 0.f;
  for (int k = 0; k < 128; ++k) { float d = hz[k] - mu2; va2 += d * d; }
  va2 /= 128.f;
  __syncthreads();
  if (tid < 128) hz[tid] = (hz[tid] - mu2) / sqrtf(va2 + 1e-5f) * g1[tid] + b1[tid];
  __syncthreads();
  if (tid < 3) {
    float o = fc2_b[tid];
    for (int k = 0; k < 128; ++k) o += hz[k] * fc2_w[tid * 128 + k];
    out[b * 3 + tid] = o;
  }
}

extern "C" void kernel_launch(void* const* d_in, const int* in_sizes, int n_in,
                              void* d_out, int out_size, void* d_ws, size_t ws_size,
                              hipStream_t stream) {
  const float* we      = (const float*)d_in[0];
  const int*   am      = (const int*)d_in[1];
  const float* hand    = (const float*)d_in[2];
  const float* w_w_in  = (const float*)d_in[3];
  const float* w_b_in  = (const float*)d_in[4];
  const float* w_w_out = (const float*)d_in[5];
  const float* w_b_out = (const float*)d_in[6];
  const float* s_w_in  = (const float*)d_in[7];
  const float* s_b_in  = (const float*)d_in[8];
  const float* s_w_out = (const float*)d_in[9];
  const float* s_b_out = (const float*)d_in[10];
  const float* c_w_in  = (const float*)d_in[11];
  const float* c_b_in  = (const float*)d_in[12];
  const float* c_w_out = (const float*)d_in[13];
  const float* c_b_out = (const float*)d_in[14];
  const float* bp_w = (const float*)d_in[15];
  const float* bp_b = (const float*)d_in[16];
  const float* hp_w = (const float*)d_in[17];
  const float* hp_b = (const float*)d_in[18];
  // d_in[19..22] = fa_* (cross-attention) — output unused by the reference, skipped.
  const float* gate_w = (const float*)d_in[23];
  const float* gate_b = (const float*)d_in[24];
  const float* fus_g  = (const float*)d_in[25];
  const float* fus_b  = (const float*)d_in[26];
  const float* fc1_w  = (const float*)d_in[27];
  const float* fc1_b  = (const float*)d_in[28];
  const float* ln1_g  = (const float*)d_in[29];
  const float* ln1_b  = (const float*)d_in[30];
  const float* fc2_w  = (const float*)d_in[31];
  const float* fc2_b  = (const float*)d_in[32];
  float* out = (float*)d_out;

  // big buffers at the bottom of the workspace
  unsigned short* qk  = (unsigned short*)d_ws;                      // [65536][1536] bf16
  unsigned short* xbf = qk + (size_t)65536 * 1536;                  // [65536][768]  bf16

  // small buffers carved from the top
  char* end = (char*)d_ws + ws_size;
  auto carveb = [&](size_t bytes) {
    size_t b = (bytes + 255) & ~(size_t)255;
    end -= b;
    return (void*)end;
  };
  unsigned short* xbarbf  = (unsigned short*)carveb((size_t)4 * 1024 * 768 * 2);
  unsigned short* obarbf  = (unsigned short*)carveb((size_t)1024 * 768 * 2);
  unsigned short* sentbf  = (unsigned short*)carveb((size_t)1024 * 768 * 2);
  unsigned short* qkv2bf  = (unsigned short*)carveb((size_t)1024 * 2304 * 2);
  float* obar2  = (float*)carveb(64 * 768 * 4);
  float* sec    = (float*)carveb(64 * 768 * 4);
  float* qkv3   = (float*)carveb(64 * 2304 * 4);
  float* obar3  = (float*)carveb(8 * 768 * 4);
  float* doc    = (float*)carveb(8 * 768 * 4);
  float* wsum   = (float*)carveb(1024 * 4);
  float* svalid = (float*)carveb(1024 * 4);
  float* cnt2   = (float*)carveb(64 * 4);
  float* secv   = (float*)carveb(64 * 4);
  float* cnt3   = (float*)carveb(8 * 4);
  unsigned short* wbf_in = (unsigned short*)carveb((size_t)2304 * 768 * 2);
  unsigned short* wobf   = (unsigned short*)carveb((size_t)768 * 768 * 2);
  unsigned short* wsbf   = (unsigned short*)carveb((size_t)2304 * 768 * 2);

  auto cgrid = [](size_t n) { size_t g = (n + 2047) / 2048; return (int)(g > 2048 ? 2048 : g); };

  // prep: weights -> bf16, mask stats
  f2bf<<<cgrid((size_t)2304 * 768), 256, 0, stream>>>(w_w_in, wbf_in, (size_t)2304 * 768);
  f2bf<<<cgrid((size_t)768 * 768), 256, 0, stream>>>(w_w_out, wobf, (size_t)768 * 768);
  f2bf<<<cgrid((size_t)2304 * 768), 256, 0, stream>>>(s_w_in, wsbf, (size_t)2304 * 768);
  mask_stats1<<<4, 256, 0, stream>>>(am, wsum, svalid);
  mask_stats2<<<1, 64, 0, stream>>>(wsum, svalid, cnt2, secv, cnt3);

  // word level
  f2bf<<<2048, 256, 0, stream>>>(we, xbf, (size_t)65536 * 768);
  gemm8<<<(65536 / 256) * (1536 / 256), 512, 0, stream>>>(xbf, wbf_in, w_b_in, qk,
                                                          65536, 1536, 768);
  attn_qk<<<1024, 256, 0, stream>>>(qk, xbf, am, wsum, xbarbf);
  // V-projection (batched per head): obar[n, h*192+c] = xbar[h][n,:] @ Wv_h^T + bv*sfac
  gemm_bf16_64<<<dim3(3, 8, 4), 256, 0, stream>>>(
      xbarbf, wbf_in + (size_t)1536 * 768, w_b_in + 1536, wsum, nullptr, obarbf,
      768, 768, (size_t)1024 * 768, (size_t)192 * 768, 192);
  // sent = obar @ w_out^T + b_out * sfac
  gemm_bf16_64<<<dim3(12, 8, 1), 256, 0, stream>>>(
      obarbf, wobf, w_b_out, wsum, nullptr, sentbf, 768, 768, 0, 0, 0);
  // sentence level QKV
  gemm_bf16_64<<<dim3(36, 8, 1), 256, 0, stream>>>(
      sentbf, wsbf, s_b_in, nullptr, nullptr, qkv2bf, 768, 2304, 0, 0, 0);
  small_attn<<<dim3(64, 4), 256, 0, stream>>>(qkv2bf, svalid, cnt2, obar2, 16);
  gemm_nt<<<dim3(12, 1), 256, 0, stream>>>(obar2, s_w_out, s_b_out, cnt2, sec,
                                           64, 768, 768, 768, 768);
  // section level
  gemm_nt<<<dim3(36, 1), 256, 0, stream>>>(sec, c_w_in, c_b_in, nullptr, qkv3,
                                           64, 2304, 768, 768, 2304);
  small_attn<<<dim3(8, 4), 256, 0, stream>>>(qkv3, secv, cnt3, obar3, 8);
  gemm_nt<<<dim3(12, 1), 256, 0, stream>>>(obar3, c_w_out, c_b_out, cnt3, doc,
                                           8, 768, 768, 768, 768);
  // fusion head
  head_kernel<<<8, 256, 0, stream>>>(doc, hand, bp_w, bp_b, hp_w, hp_b, gate_w, gate_b,
                                     fus_g, fus_b, fc1_w, fc1_b, ln1_g, ln1_b, fc2_w, fc2_b, out);
}